// Round 11
// baseline (123.934 us; speedup 1.0000x reference)
//
#include <hip/hip_runtime.h>
#include <hip/hip_bf16.h>
#include <cmath>

typedef unsigned short u16;
typedef __bf16 bf16x8 __attribute__((ext_vector_type(8)));
typedef float  f32x4  __attribute__((ext_vector_type(4)));
typedef float  f4     __attribute__((ext_vector_type(4)));
typedef u16    us4    __attribute__((ext_vector_type(4)));

#define DEVFN __device__ __forceinline__

static constexpr int Bq = 2, Nq = 2048, Eq = 1024;
static constexpr int Mq = Bq * Nq;        // 4096 tokens
static constexpr int CHK = 64;            // attention chunk
static constexpr int NC  = Nq / CHK;      // 32 chunks
static constexpr int BH  = Bq * 16;       // 32

DEVFN u16 f2b(float f) {                  // f32 -> bf16 (RNE), finite inputs
    union { float f; unsigned int u; } x; x.f = f;
    unsigned int r = x.u + 0x7fffu + ((x.u >> 16) & 1u);
    return (u16)(r >> 16);
}
DEVFN float b2f(u16 v) {
    union { unsigned int u; float f; } x; x.u = ((unsigned int)v) << 16; return x.f;
}

DEVFN void gl_lds16(const u16* g, u16* l) {  // async 16B global->LDS (dest: wave base + lane*16)
    __builtin_amdgcn_global_load_lds(
        (const __attribute__((address_space(1))) unsigned int*)(g),
        (__attribute__((address_space(3))) unsigned int*)(l),
        16, 0, 0);
}

// ---------------- all f32 -> bf16 converts in ONE launch ----------------
__global__ __launch_bounds__(256)
void cvt_all_kernel(const float* __restrict__ x,
                    const float* __restrict__ w0, const float* __restrict__ w1,
                    const float* __restrict__ w2, const float* __restrict__ w3,
                    u16* __restrict__ Xb, u16* __restrict__ Wb)
{
    const int blk = blockIdx.x;
    const float* s; u16* d; int i;
    if (blk < 4096) {
        i = blk * 256 + threadIdx.x;  s = x;  d = Xb;
    } else {
        const int wsel = (blk - 4096) >> 10;
        i = ((blk - 4096) & 1023) * 256 + threadIdx.x;
        s = (wsel == 0) ? w0 : (wsel == 1) ? w1 : (wsel == 2) ? w2 : w3;
        d = Wb + (size_t)wsel * (Eq * Eq);
    }
    f4 v = *reinterpret_cast<const f4*>(&s[(size_t)i * 4]);
    us4 p; p[0] = f2b(v[0]); p[1] = f2b(v[1]); p[2] = f2b(v[2]); p[3] = f2b(v[3]);
    *reinterpret_cast<us4*>(&d[(size_t)i * 4]) = p;
}

// ======== half-direct ring GEMM: B via LDS ring-3, A direct global->VGPR ========
// MODE 0: fused QKV, BM=128 (8 waves of 32x64), N=3072, grid 768.
// MODE 1: O-projection, BM=64 (8 waves of 16x64), N=1024, f32 out, grid 512.
// Per tile t: stage B(t+2) [1 gl_lds/thread]; prefetch A(t+1) -> regs (2-deep
// ping-pong, unrolled x2, static regs); ds_read 4 B-frags; MFMA; counted
// vmcnt(1+MI) = {B(t+2), A(t+1)} stay in flight; s_barrier.
// LDS read port/CU/tile: 32 x b128 (was 48) — the R10-measured bottleneck.
template<int MODE>
__global__ __launch_bounds__(512, 4)
void gemm_hd(const u16* __restrict__ X, const u16* __restrict__ W,
             const float* __restrict__ b0, const float* __restrict__ b1,
             const float* __restrict__ b2,
             u16* __restrict__ Qb, u16* __restrict__ Kb, u16* __restrict__ KbT,
             u16* __restrict__ VbT, float* __restrict__ outF)
{
    constexpr int MI = (MODE == 0) ? 2 : 1;      // A-frags per wave
    constexpr int WR = (MODE == 0) ? 32 : 16;    // wave rows
    __shared__ u16 lds[3 * 4096];                // 24KB: 3 ring bufs of B (128x32)
    const int tid = threadIdx.x, wid = tid >> 6, lane = tid & 63;
    const int wr = (wid >> 1) * WR, wc = (wid & 1) * 64;
    const int fr = lane & 15, fq = lane >> 4;

    const int bid = blockIdx.x;
    const int fid = (MODE == 0) ? ((bid & 7) * 96 + (bid >> 3))
                                : ((bid & 7) * 64 + (bid >> 3));
    const int bx  = (MODE == 0) ? (fid % 24) : (fid & 7);
    const int by  = (MODE == 0) ? (fid / 24) : (fid >> 3);
    const int m0  = by * ((MODE == 0) ? 128 : 64), n0 = bx * 128;

    // B staging: 512 thr x 16B = full 128x32 tile per round (1 gl_lds/thread)
    const int row0 = tid >> 2;
    const int sc   = ((tid & 3) ^ ((row0 >> 1) & 3)) * 8;   // swizzled source slot
    const u16* gB = W + (size_t)(n0 + row0) * 1024 + sc;
    const int dw = wid * 512;

    // B-frag reads: same involution (R6-proven 0-conflict)
    const int fsw = (fq ^ ((fr >> 1) & 3)) << 3;
    int boff[4];
#pragma unroll
    for (int ni = 0; ni < 4; ++ni) boff[ni] = (wc + ni * 16 + fr) * 32 + fsw;

    // A direct per-lane frag pointers: 16 rows x 64B lines, L2-resident panel
    const u16* pa[MI];
#pragma unroll
    for (int mi = 0; mi < MI; ++mi)
        pa[mi] = X + (size_t)(m0 + wr + mi * 16 + fr) * 1024 + fq * 8;

#define STB(kt, bs) gl_lds16(gB + (kt) * 32, lds + (bs) * 4096 + dw)
#define VMW(n) asm volatile("s_waitcnt vmcnt(" #n ")" ::: "memory")

    f32x4 acc[MI][4] = {};
    bf16x8 aX[MI], aY[MI];
    int cb = 0, sb = 2;

    // prologue: B(0),B(1) staged; A(0) loaded; B(0) landed (keep B(1)+A(0))
    STB(0, 0);
    STB(1, 1);
#pragma unroll
    for (int mi = 0; mi < MI; ++mi)
        aX[mi] = *reinterpret_cast<const bf16x8*>(pa[mi]);
    if (MODE == 0) VMW(3); else VMW(2);
    __builtin_amdgcn_sched_barrier(0);
    __builtin_amdgcn_s_barrier();

#define ITER(T, AUSE, APRE) do {                                               \
        if ((T) + 2 < 32) STB((T) + 2, sb);                                    \
        if ((T) + 1 < 32) {                                                    \
            _Pragma("unroll")                                                  \
            for (int mi = 0; mi < MI; ++mi)                                    \
                APRE[mi] = *reinterpret_cast<const bf16x8*>(                   \
                    pa[mi] + ((T) + 1) * 32);                                  \
        }                                                                      \
        const u16* buf = lds + cb * 4096;                                      \
        bf16x8 bfv[4];                                                         \
        _Pragma("unroll")                                                      \
        for (int ni = 0; ni < 4; ++ni)                                         \
            bfv[ni] = *reinterpret_cast<const bf16x8*>(&buf[boff[ni]]);        \
        __builtin_amdgcn_s_setprio(1);                                         \
        _Pragma("unroll")                                                      \
        for (int mi = 0; mi < MI; ++mi)                                        \
            _Pragma("unroll")                                                  \
            for (int ni = 0; ni < 4; ++ni)                                     \
                acc[mi][ni] = __builtin_amdgcn_mfma_f32_16x16x32_bf16(         \
                    AUSE[mi], bfv[ni], acc[mi][ni], 0, 0, 0);                  \
        __builtin_amdgcn_s_setprio(0);                                         \
        if ((T) < 30)       { if (MODE == 0) VMW(3); else VMW(2); }            \
        else if ((T) == 30) { if (MODE == 0) VMW(2); else VMW(1); }            \
        __builtin_amdgcn_sched_barrier(0);                                     \
        __builtin_amdgcn_s_barrier();                                          \
        cb = (cb == 2) ? 0 : cb + 1;                                           \
        sb = (sb == 2) ? 0 : sb + 1;                                           \
    } while (0)

#pragma unroll 2
    for (int t2 = 0; t2 < 32; t2 += 2) {
        ITER(t2,     aX, aY);     // compute with aX, prefetch into aY
        ITER(t2 + 1, aY, aX);     // compute with aY, prefetch into aX
    }
#undef ITER
#undef STB
#undef VMW

    if (MODE == 0) {
        const int nw  = n0 + wc;                           // seg-uniform
        const int seg = nw >> 10;                          // 0=q 1=k 2=v
        const float* bp = (seg == 0) ? b0 : (seg == 1) ? b1 : b2;
#pragma unroll
        for (int mi = 0; mi < MI; ++mi)
#pragma unroll
            for (int ni = 0; ni < 4; ++ni) {
                const int nl    = (nw & 1023) + ni * 16 + fr;
                const int mbase = m0 + wr + mi * 16 + fq * 4;
                const float bn  = bp[nl];
                float vr[4];
#pragma unroll
                for (int r = 0; r < 4; ++r) {
                    float v = acc[mi][ni][r] + bn;
                    if (seg < 2) v = (v > 0.f) ? (v + 1.f) : __expf(v);  // elu+1
                    vr[r] = v;
                }
                if (seg == 0) {
#pragma unroll
                    for (int r = 0; r < 4; ++r)
                        Qb[(size_t)(mbase + r) * 1024 + nl] = f2b(vr[r]);
                } else {
                    us4 pk;
#pragma unroll
                    for (int r = 0; r < 4; ++r) pk[r] = f2b(vr[r]);
                    const int bb = mbase >> 11, nt = mbase & 2047;
                    const int hh = nl >> 6,     dd = nl & 63;
                    u16* T = (seg == 1) ? KbT : VbT;
                    *reinterpret_cast<us4*>(
                        &T[((size_t)(bb * 16 + hh) * 64 + dd) * 2048 + nt]) = pk;
                    if (seg == 1) {
#pragma unroll
                        for (int r = 0; r < 4; ++r)
                            Kb[(size_t)(mbase + r) * 1024 + nl] = f2b(vr[r]);
                    }
                }
            }
    } else {
#pragma unroll
        for (int mi = 0; mi < MI; ++mi)
#pragma unroll
            for (int ni = 0; ni < 4; ++ni) {
                const int n     = n0 + wc + ni * 16 + fr;
                const int mbase = m0 + wr + mi * 16 + fq * 4;
                const float bn  = b0[n];
#pragma unroll
                for (int r = 0; r < 4; ++r)
                    outF[(size_t)(mbase + r) * 1024 + n] = acc[mi][ni][r] + bn;
            }
    }
}

// ---------------- per-chunk KV^T = v^T @ k: KVT[de][dk], bf16 out ----------------
__global__ __launch_bounds__(64)
void chunk_kv_kernel(const u16* __restrict__ KbT, const u16* __restrict__ VbT,
                     u16* __restrict__ KVT)
{
    const int blk = blockIdx.x;          // bh*NC + c
    const int bh = blk >> 5, c = blk & 31;
    const int lane = threadIdx.x;
    const int fr = lane & 15, fq = lane >> 4, fk = fq * 8;
    const u16* kt = KbT + (size_t)bh * 64 * 2048;
    const u16* vt = VbT + (size_t)bh * 64 * 2048;

    bf16x8 a[4][2], b[4][2];             // a = V rows (de), b = K rows (dk)
#pragma unroll
    for (int mi = 0; mi < 4; ++mi)
#pragma unroll
        for (int kh = 0; kh < 2; ++kh)
            a[mi][kh] = *reinterpret_cast<const bf16x8*>(
                &vt[(size_t)(mi * 16 + fr) * 2048 + c * 64 + kh * 32 + fk]);
#pragma unroll
    for (int ni = 0; ni < 4; ++ni)
#pragma unroll
        for (int kh = 0; kh < 2; ++kh)
            b[ni][kh] = *reinterpret_cast<const bf16x8*>(
                &kt[(size_t)(ni * 16 + fr) * 2048 + c * 64 + kh * 32 + fk]);

    f32x4 acc[4][4] = {};
    __builtin_amdgcn_s_setprio(1);
#pragma unroll
    for (int mi = 0; mi < 4; ++mi)
#pragma unroll
        for (int ni = 0; ni < 4; ++ni)
#pragma unroll
            for (int kh = 0; kh < 2; ++kh)
                acc[mi][ni] = __builtin_amdgcn_mfma_f32_16x16x32_bf16(
                    a[mi][kh], b[ni][kh], acc[mi][ni], 0, 0, 0);
    __builtin_amdgcn_s_setprio(0);

    u16* out = KVT + (size_t)blk * 4096;   // [de][dk] bf16
#pragma unroll
    for (int mi = 0; mi < 4; ++mi)
#pragma unroll
        for (int ni = 0; ni < 4; ++ni)
#pragma unroll
            for (int r = 0; r < 4; ++r)
                out[(mi * 16 + fq * 4 + r) * 64 + ni * 16 + fr] = f2b(acc[mi][ni][r]);
}

// ---------------- elementwise exclusive scan over chunks (bf16 in/out) ----------------
__global__ __launch_bounds__(256)
void scan_kernel(const u16* __restrict__ KVT, u16* __restrict__ STb)
{
    const int bh = blockIdx.x >> 4, sl = blockIdx.x & 15;
    const int el = sl * 256 + threadIdx.x;              // element of [de][dk]
    const u16* src = KVT + (size_t)bh * NC * 4096 + el;
    u16*      dst  = STb + (size_t)bh * NC * 4096 + el;
    float run = 0.f;
#pragma unroll 4
    for (int c = 0; c < NC; ++c) {
        dst[(size_t)c * 4096] = f2b(run);               // exclusive prefix
        run += b2f(src[(size_t)c * 4096]);
    }
}

// ---------------- per-chunk attention output ----------------
__global__ __launch_bounds__(64)
void attn_kernel(const u16* __restrict__ Qb, const u16* __restrict__ Kb,
                 const u16* __restrict__ VbT, const u16* __restrict__ STb,
                 u16* __restrict__ Ob)
{
    __shared__ u16 P[64 * 72];   // stride 72 u16 = 144B: 16B-aligned, 2-way banks
    const int blk = blockIdx.x;
    const int bh = blk >> 5, c = blk & 31;
    const int b = bh >> 4, h = bh & 15;
    const int lane = threadIdx.x;
    const int fr = lane & 15, fq = lane >> 4, fk = fq * 8;
    const int tok0 = b * 2048 + c * 64;

    bf16x8 qa[4][2];
#pragma unroll
    for (int mi = 0; mi < 4; ++mi)
#pragma unroll
        for (int kh = 0; kh < 2; ++kh)
            qa[mi][kh] = *reinterpret_cast<const bf16x8*>(
                &Qb[(size_t)(tok0 + mi * 16 + fr) * 1024 + h * 64 + kh * 32 + fk]);

    // P = causal-mask(q @ k^T) -> LDS bf16
    {
        bf16x8 kb[4][2];
#pragma unroll
        for (int si = 0; si < 4; ++si)
#pragma unroll
            for (int kh = 0; kh < 2; ++kh)
                kb[si][kh] = *reinterpret_cast<const bf16x8*>(
                    &Kb[(size_t)(tok0 + si * 16 + fr) * 1024 + h * 64 + kh * 32 + fk]);
        f32x4 p[4][4] = {};
        __builtin_amdgcn_s_setprio(1);
#pragma unroll
        for (int mi = 0; mi < 4; ++mi)
#pragma unroll
            for (int si = 0; si < 4; ++si)
#pragma unroll
                for (int kh = 0; kh < 2; ++kh)
                    p[mi][si] = __builtin_amdgcn_mfma_f32_16x16x32_bf16(
                        qa[mi][kh], kb[si][kh], p[mi][si], 0, 0, 0);
        __builtin_amdgcn_s_setprio(0);
#pragma unroll
        for (int mi = 0; mi < 4; ++mi)
#pragma unroll
            for (int si = 0; si < 4; ++si)
#pragma unroll
                for (int r = 0; r < 4; ++r) {
                    int t = mi * 16 + fq * 4 + r;
                    int s = si * 16 + fr;
                    float v = (s <= t) ? p[mi][si][r] : 0.0f;
                    P[t * 72 + s] = f2b(v);
                }
    }
    __syncthreads();

    f32x4 acc[4][4] = {};
    // acc = q @ ST   (STb[de][dk], dk-contiguous)
    {
        const u16* st = STb + (size_t)blk * 4096;
        bf16x8 sb[4][2];
#pragma unroll
        for (int ni = 0; ni < 4; ++ni)
#pragma unroll
            for (int kh = 0; kh < 2; ++kh)
                sb[ni][kh] = *reinterpret_cast<const bf16x8*>(
                    &st[(ni * 16 + fr) * 64 + kh * 32 + fk]);
        __builtin_amdgcn_s_setprio(1);
#pragma unroll
        for (int mi = 0; mi < 4; ++mi)
#pragma unroll
            for (int ni = 0; ni < 4; ++ni)
#pragma unroll
                for (int kh = 0; kh < 2; ++kh)
                    acc[mi][ni] = __builtin_amdgcn_mfma_f32_16x16x32_bf16(
                        qa[mi][kh], sb[ni][kh], acc[mi][ni], 0, 0, 0);
        __builtin_amdgcn_s_setprio(0);
    }
    // acc += P @ v
    {
        const u16* vt = VbT + (size_t)bh * 64 * 2048;
#pragma unroll
        for (int sh = 0; sh < 2; ++sh) {
            bf16x8 pa[4], vb[4];
#pragma unroll
            for (int mi = 0; mi < 4; ++mi)
                pa[mi] = *reinterpret_cast<const bf16x8*>(
                    &P[(mi * 16 + fr) * 72 + sh * 32 + fk]);
#pragma unroll
            for (int ni = 0; ni < 4; ++ni)
                vb[ni] = *reinterpret_cast<const bf16x8*>(
                    &vt[(size_t)(ni * 16 + fr) * 2048 + c * 64 + sh * 32 + fk]);
            __builtin_amdgcn_s_setprio(1);
#pragma unroll
            for (int mi = 0; mi < 4; ++mi)
#pragma unroll
                for (int ni = 0; ni < 4; ++ni)
                    acc[mi][ni] = __builtin_amdgcn_mfma_f32_16x16x32_bf16(
                        pa[mi], vb[ni], acc[mi][ni], 0, 0, 0);
            __builtin_amdgcn_s_setprio(0);
        }
    }
    // write token-major bf16 O
#pragma unroll
    for (int mi = 0; mi < 4; ++mi)
#pragma unroll
        for (int ni = 0; ni < 4; ++ni)
#pragma unroll
            for (int r = 0; r < 4; ++r) {
                int t = tok0 + mi * 16 + fq * 4 + r;
                int n = h * 64 + ni * 16 + fr;
                Ob[(size_t)t * 1024 + n] = f2b(acc[mi][ni][r]);
            }
}

extern "C" void kernel_launch(void* const* d_in, const int* in_sizes, int n_in,
                              void* d_out, int out_size, void* d_ws, size_t ws_size,
                              hipStream_t stream)
{
    (void)in_sizes; (void)n_in; (void)out_size; (void)ws_size;
    const float* x  = (const float*)d_in[0];
    const float* Wq = (const float*)d_in[1];
    const float* bq = (const float*)d_in[2];
    const float* Wk = (const float*)d_in[3];
    const float* bk = (const float*)d_in[4];
    const float* Wv = (const float*)d_in[5];
    const float* bv = (const float*)d_in[6];
    const float* Wo = (const float*)d_in[7];
    const float* bo = (const float*)d_in[8];
    float* out = (float*)d_out;

    char* ws = (char*)d_ws;
    constexpr size_t SZ_ME = (size_t)Mq * Eq * 2;        // 8 MB
    u16*   Qb  = (u16*)  (ws + 0 * SZ_ME);
    u16*   Kb  = (u16*)  (ws + 1 * SZ_ME);
    u16*   KbT = (u16*)  (ws + 2 * SZ_ME);
    u16*   VbT = (u16*)  (ws + 3 * SZ_ME);
    u16*   Ob  = (u16*)  (ws + 4 * SZ_ME);
    u16*   KVT = (u16*)  (ws + 5 * SZ_ME);               // 8 MB bf16
    u16*   STb = (u16*)  (ws + 6 * SZ_ME);
    u16*   Xb  = (u16*)  (ws + 7 * SZ_ME);
    u16*   Wb0 = (u16*)  (ws + 8 * SZ_ME);               // [Wq|Wk|Wv|Wo] bf16
    u16* Wqkvb = Wb0;
    u16* Wob   = Wb0 + (size_t)3 * Eq * Eq;

    // 1) all bf16 conversions, one launch
    cvt_all_kernel<<<dim3(8192), dim3(256), 0, stream>>>(x, Wq, Wk, Wv, Wo, Xb, Wb0);

    // 2) fused QKV projection (M=4096, N=3072): half-direct ring, 768 x 512 thr
    gemm_hd<0><<<dim3(768), dim3(512), 0, stream>>>(
        Xb, Wqkvb, bq, bk, bv, Qb, Kb, KbT, VbT, nullptr);

    // 3) attention
    chunk_kv_kernel<<<dim3(BH * NC), dim3(64), 0, stream>>>(KbT, VbT, KVT);
    scan_kernel<<<dim3(BH * 16), dim3(256), 0, stream>>>(KVT, STb);
    attn_kernel<<<dim3(BH * NC), dim3(64), 0, stream>>>(Qb, Kb, VbT, STb, Ob);

    // 4) output projection (M=4096, N=1024): half-direct ring, 512 x 512 thr
    gemm_hd<1><<<dim3(512), dim3(512), 0, stream>>>(
        Ob, Wob, bo, nullptr, nullptr, nullptr, nullptr, nullptr, nullptr, out);
}

// Round 12
// 100.882 us; speedup vs baseline: 1.2285x; 1.2285x over previous
//
#include <hip/hip_runtime.h>
#include <hip/hip_bf16.h>
#include <cmath>

typedef unsigned short u16;
typedef __bf16 bf16x8 __attribute__((ext_vector_type(8)));
typedef float  f32x4  __attribute__((ext_vector_type(4)));
typedef float  f4     __attribute__((ext_vector_type(4)));
typedef u16    us4    __attribute__((ext_vector_type(4)));

#define DEVFN __device__ __forceinline__

static constexpr int Bq = 2, Nq = 2048, Eq = 1024;
static constexpr int Mq = Bq * Nq;        // 4096 tokens
static constexpr int CHK = 64;            // attention chunk
static constexpr int NC  = Nq / CHK;      // 32 chunks
static constexpr int BH  = Bq * 16;       // 32

DEVFN u16 f2b(float f) {                  // f32 -> bf16 (RNE), finite inputs
    union { float f; unsigned int u; } x; x.f = f;
    unsigned int r = x.u + 0x7fffu + ((x.u >> 16) & 1u);
    return (u16)(r >> 16);
}
DEVFN float b2f(u16 v) {
    union { unsigned int u; float f; } x; x.u = ((unsigned int)v) << 16; return x.f;
}

DEVFN void gl_lds16(const u16* g, u16* l) {  // async 16B global->LDS (dest: wave base + lane*16)
    __builtin_amdgcn_global_load_lds(
        (const __attribute__((address_space(1))) unsigned int*)(g),
        (__attribute__((address_space(3))) unsigned int*)(l),
        16, 0, 0);
}

// ---------------- all f32 -> bf16 converts in ONE launch ----------------
__global__ __launch_bounds__(256)
void cvt_all_kernel(const float* __restrict__ x,
                    const float* __restrict__ w0, const float* __restrict__ w1,
                    const float* __restrict__ w2, const float* __restrict__ w3,
                    u16* __restrict__ Xb, u16* __restrict__ Wb)
{
    const int blk = blockIdx.x;
    const float* s; u16* d; int i;
    if (blk < 4096) {
        i = blk * 256 + threadIdx.x;  s = x;  d = Xb;
    } else {
        const int wsel = (blk - 4096) >> 10;
        i = ((blk - 4096) & 1023) * 256 + threadIdx.x;
        s = (wsel == 0) ? w0 : (wsel == 1) ? w1 : (wsel == 2) ? w2 : w3;
        d = Wb + (size_t)wsel * (Eq * Eq);
    }
    f4 v = *reinterpret_cast<const f4*>(&s[(size_t)i * 4]);
    us4 p; p[0] = f2b(v[0]); p[1] = f2b(v[1]); p[2] = f2b(v[2]); p[3] = f2b(v[3]);
    *reinterpret_cast<us4*>(&d[(size_t)i * 4]) = p;
}

// ======== QKV ring GEMM: 128x128 tile, 8 waves (32x64 each), BK=32, ring-3 ========
// R10-exact (best measured: 43.2 us). 512 thr -> 24 waves/CU; 2 gl_lds/tile;
// steady vmcnt(2); swizzle sigma(row)=(row>>1)&3 both sides (0 conflicts).
__global__ __launch_bounds__(512, 4)
void qkv_ring(const u16* __restrict__ X, const u16* __restrict__ W,
              const float* __restrict__ b0, const float* __restrict__ b1,
              const float* __restrict__ b2,
              u16* __restrict__ Qb, u16* __restrict__ Kb, u16* __restrict__ KbT,
              u16* __restrict__ VbT)
{
    constexpr int BUFU = 8192;                // 16KB: A 4096 u16 | B 4096 u16
    __shared__ u16 lds[3 * BUFU];             // 48KB -> 3 blocks/CU
    const int tid = threadIdx.x, wid = tid >> 6, lane = tid & 63;
    const int wr = (wid >> 1) * 32, wc = (wid & 1) * 64;   // wave: 32 rows x 64 cols
    const int fr = lane & 15, fq = lane >> 4;

    const int bid = blockIdx.x;               // grid 768 = 8 * 96 (XCD-bijective)
    const int fid = (bid & 7) * 96 + (bid >> 3);
    const int bx = fid % 24, by = fid / 24;
    const int m0 = by * 128, n0 = bx * 128;

    // staging: one round = 512 thr x 16B = 128 rows x 4 slots (full matrix)
    const int row0 = tid >> 2;
    const int sc   = ((tid & 3) ^ ((row0 >> 1) & 3)) * 8;   // swizzled source slot
    const u16* gA = X + (size_t)(m0 + row0) * 1024 + sc;
    const u16* gB = W + (size_t)(n0 + row0) * 1024 + sc;
    const int dw = wid * 512;                 // wave-uniform dest piece (1KB/wave)

    // fragment reads: same involution on read side
    const int fsw = (fq ^ ((fr >> 1) & 3)) << 3;
    int aoff[2], boff[4];
#pragma unroll
    for (int mi = 0; mi < 2; ++mi) aoff[mi] = (wr + mi * 16 + fr) * 32 + fsw;
#pragma unroll
    for (int ni = 0; ni < 4; ++ni) boff[ni] = 4096 + (wc + ni * 16 + fr) * 32 + fsw;

#define STAGE(kt, bs) do { u16* _b = lds + (bs) * BUFU;                        \
        gl_lds16(gA + (kt) * 32, _b + dw);                                     \
        gl_lds16(gB + (kt) * 32, _b + 4096 + dw); } while (0)

    // prologue: tiles 0,1 staged (4 loads); wait tile0 (tile1's 2 stay in flight)
    STAGE(0, 0);
    STAGE(1, 1);
    asm volatile("s_waitcnt vmcnt(2)" ::: "memory");
    __builtin_amdgcn_sched_barrier(0);
    __builtin_amdgcn_s_barrier();

    f32x4 acc[2][4] = {};
    int cb = 0, sb = 2;

    for (int t = 0; t < 32; ++t) {
        if (t + 2 < 32) STAGE(t + 2, sb);
        const u16* buf = lds + cb * BUFU;
        bf16x8 af[2], bfv[4];
#pragma unroll
        for (int mi = 0; mi < 2; ++mi)
            af[mi] = *reinterpret_cast<const bf16x8*>(&buf[aoff[mi]]);
#pragma unroll
        for (int ni = 0; ni < 4; ++ni)
            bfv[ni] = *reinterpret_cast<const bf16x8*>(&buf[boff[ni]]);
        __builtin_amdgcn_s_setprio(1);
#pragma unroll
        for (int mi = 0; mi < 2; ++mi)
#pragma unroll
            for (int ni = 0; ni < 4; ++ni)
                acc[mi][ni] = __builtin_amdgcn_mfma_f32_16x16x32_bf16(
                    af[mi], bfv[ni], acc[mi][ni], 0, 0, 0);
        __builtin_amdgcn_s_setprio(0);
        // tile boundary: t+1 landed; keep t+2's 2 loads in flight
        if (t < 30)       asm volatile("s_waitcnt vmcnt(2)" ::: "memory");
        else if (t == 30) asm volatile("s_waitcnt vmcnt(0)" ::: "memory");
        __builtin_amdgcn_sched_barrier(0);
        __builtin_amdgcn_s_barrier();
        cb = (cb == 2) ? 0 : cb + 1;
        sb = (sb == 2) ? 0 : sb + 1;
    }
#undef STAGE

    const int nw  = n0 + wc;                           // 64-aligned, seg-uniform
    const int seg = nw >> 10;                          // 0=q 1=k 2=v
    const float* bp = (seg == 0) ? b0 : (seg == 1) ? b1 : b2;
#pragma unroll
    for (int mi = 0; mi < 2; ++mi)
#pragma unroll
        for (int ni = 0; ni < 4; ++ni) {
            const int nl    = (nw & 1023) + ni * 16 + fr;
            const int mbase = m0 + wr + mi * 16 + fq * 4;
            const float bn  = bp[nl];
            float vr[4];
#pragma unroll
            for (int r = 0; r < 4; ++r) {
                float v = acc[mi][ni][r] + bn;
                if (seg < 2) v = (v > 0.f) ? (v + 1.f) : __expf(v);  // elu+1
                vr[r] = v;
            }
            if (seg == 0) {
#pragma unroll
                for (int r = 0; r < 4; ++r)
                    Qb[(size_t)(mbase + r) * 1024 + nl] = f2b(vr[r]);
            } else {
                us4 pk;
#pragma unroll
                for (int r = 0; r < 4; ++r) pk[r] = f2b(vr[r]);
                const int bb = mbase >> 11, nt = mbase & 2047;
                const int hh = nl >> 6,     dd = nl & 63;
                u16* T = (seg == 1) ? KbT : VbT;
                *reinterpret_cast<us4*>(
                    &T[((size_t)(bb * 16 + hh) * 64 + dd) * 2048 + nt]) = pk;
                if (seg == 1) {
#pragma unroll
                    for (int r = 0; r < 4; ++r)
                        Kb[(size_t)(mbase + r) * 1024 + nl] = f2b(vr[r]);
                }
            }
        }
}

// ======== O-proj: 64x128 tile, 4 waves, BK=32, ring-3, dup-free (R8/R10, verified) ========
__global__ __launch_bounds__(256)
void oproj_kernel(const u16* __restrict__ X, const u16* __restrict__ W,
                  const float* __restrict__ b0, float* __restrict__ outF)
{
    constexpr int BUFU = (64 + 128) * 32;     // 6144 u16 = 12KB per buffer
    __shared__ u16 lds[3 * BUFU];             // 36KB
    const int tid = threadIdx.x, wid = tid >> 6, lane = tid & 63;
    const int wr = (wid >> 1) * 32, wc = (wid & 1) * 64;
    const int fr = lane & 15, fq = lane >> 4;

    const int bid = blockIdx.x;               // grid 512 = 8 * 64
    const int fid = (bid & 7) * 64 + (bid >> 3);
    const int bx = fid & 7, by = fid >> 3;
    const int m0 = by * 64, n0 = bx * 128;

    const int ra = tid >> 2;
    const int sc = ((tid & 3) ^ ((tid >> 3) & 3)) * 8;
    const u16* gA = X + (size_t)(m0 + ra) * 1024 + sc;
    const u16* gB = W + (size_t)(n0 + ra) * 1024 + sc;
    const int dw = wid * 512;

    const int fsw = (fq ^ ((fr >> 1) & 3)) << 3;
    int aoff[2], boff[4];
#pragma unroll
    for (int mi = 0; mi < 2; ++mi) aoff[mi] = (wr + mi * 16 + fr) * 32 + fsw;
#pragma unroll
    for (int ni = 0; ni < 4; ++ni) boff[ni] = 2048 + (wc + ni * 16 + fr) * 32 + fsw;

#define STAGE(kt, bs) do { u16* _b = lds + (bs) * BUFU;                          \
        gl_lds16(gA + (kt) * 32,             _b + dw);                           \
        gl_lds16(gB + (kt) * 32,             _b + 2048 + dw);                    \
        gl_lds16(gB + (kt) * 32 + 64 * 1024, _b + 4096 + dw); } while (0)

    STAGE(0, 0);
    STAGE(1, 1);
    asm volatile("s_waitcnt vmcnt(3)" ::: "memory");
    __builtin_amdgcn_sched_barrier(0);
    __builtin_amdgcn_s_barrier();

    f32x4 acc[2][4] = {};
    int cb = 0, sb = 2;

    for (int t = 0; t < 32; ++t) {
        if (t + 2 < 32) STAGE(t + 2, sb);
        const u16* buf = lds + cb * BUFU;
        bf16x8 af[2], bfv[4];
#pragma unroll
        for (int mi = 0; mi < 2; ++mi)
            af[mi] = *reinterpret_cast<const bf16x8*>(&buf[aoff[mi]]);
#pragma unroll
        for (int ni = 0; ni < 4; ++ni)
            bfv[ni] = *reinterpret_cast<const bf16x8*>(&buf[boff[ni]]);
        __builtin_amdgcn_s_setprio(1);
#pragma unroll
        for (int mi = 0; mi < 2; ++mi)
#pragma unroll
            for (int ni = 0; ni < 4; ++ni)
                acc[mi][ni] = __builtin_amdgcn_mfma_f32_16x16x32_bf16(
                    af[mi], bfv[ni], acc[mi][ni], 0, 0, 0);
        __builtin_amdgcn_s_setprio(0);
        if (t < 30)       asm volatile("s_waitcnt vmcnt(3)" ::: "memory");
        else if (t == 30) asm volatile("s_waitcnt vmcnt(0)" ::: "memory");
        __builtin_amdgcn_sched_barrier(0);
        __builtin_amdgcn_s_barrier();
        cb = (cb == 2) ? 0 : cb + 1;
        sb = (sb == 2) ? 0 : sb + 1;
    }
#undef STAGE

#pragma unroll
    for (int mi = 0; mi < 2; ++mi)
#pragma unroll
        for (int ni = 0; ni < 4; ++ni) {
            const int n     = n0 + wc + ni * 16 + fr;
            const int mbase = m0 + wr + mi * 16 + fq * 4;
            const float bn  = b0[n];
#pragma unroll
            for (int r = 0; r < 4; ++r)
                outF[(size_t)(mbase + r) * 1024 + n] = acc[mi][ni][r] + bn;
        }
}

// ======== fused chunk-KV + exclusive scan: one wave per (bh, 16-row de slice) ========
// Per chunk c: cur[de 16][dk 64] = V^T_slice @ K (MFMA over 64 tokens);
// write f2b(run) (exclusive prefix) to STb[bh*NC+c][de*64+dk]; run += cur (f32).
// Prefix state lives in VGPRs — no KVT buffer, no second pass, more precise.
__global__ __launch_bounds__(64)
void kv_scan_kernel(const u16* __restrict__ KbT, const u16* __restrict__ VbT,
                    u16* __restrict__ STb)
{
    const int blk = blockIdx.x;               // bh*4 + ds  (128 blocks)
    const int bh = blk >> 2, ds = blk & 3;
    const int lane = threadIdx.x;
    const int fr = lane & 15, fq = lane >> 4, fk = fq * 8;
    const u16* kt = KbT + (size_t)bh * 64 * 2048;
    const u16* vt = VbT + (size_t)bh * 64 * 2048 + (size_t)(ds * 16 + fr) * 2048;

    f32x4 run[4] = {};
    for (int c = 0; c < NC; ++c) {
        bf16x8 a[2], b[4][2];
#pragma unroll
        for (int kh = 0; kh < 2; ++kh)
            a[kh] = *reinterpret_cast<const bf16x8*>(&vt[c * 64 + kh * 32 + fk]);
#pragma unroll
        for (int ni = 0; ni < 4; ++ni)
#pragma unroll
            for (int kh = 0; kh < 2; ++kh)
                b[ni][kh] = *reinterpret_cast<const bf16x8*>(
                    &kt[(size_t)(ni * 16 + fr) * 2048 + c * 64 + kh * 32 + fk]);
        f32x4 cur[4] = {};
#pragma unroll
        for (int ni = 0; ni < 4; ++ni)
#pragma unroll
            for (int kh = 0; kh < 2; ++kh)
                cur[ni] = __builtin_amdgcn_mfma_f32_16x16x32_bf16(
                    a[kh], b[ni][kh], cur[ni], 0, 0, 0);
        u16* dst = STb + (size_t)(bh * NC + c) * 4096 + ds * 16 * 64;
#pragma unroll
        for (int ni = 0; ni < 4; ++ni)
#pragma unroll
            for (int r = 0; r < 4; ++r) {
                dst[(fq * 4 + r) * 64 + ni * 16 + fr] = f2b(run[ni][r]);
                run[ni][r] += cur[ni][r];
            }
    }
}

// ---------------- per-chunk attention output ----------------
__global__ __launch_bounds__(64)
void attn_kernel(const u16* __restrict__ Qb, const u16* __restrict__ Kb,
                 const u16* __restrict__ VbT, const u16* __restrict__ STb,
                 u16* __restrict__ Ob)
{
    __shared__ u16 P[64 * 72];   // stride 72 u16 = 144B: 16B-aligned, 2-way banks
    const int blk = blockIdx.x;
    const int bh = blk >> 5, c = blk & 31;
    const int b = bh >> 4, h = bh & 15;
    const int lane = threadIdx.x;
    const int fr = lane & 15, fq = lane >> 4, fk = fq * 8;
    const int tok0 = b * 2048 + c * 64;

    bf16x8 qa[4][2];
#pragma unroll
    for (int mi = 0; mi < 4; ++mi)
#pragma unroll
        for (int kh = 0; kh < 2; ++kh)
            qa[mi][kh] = *reinterpret_cast<const bf16x8*>(
                &Qb[(size_t)(tok0 + mi * 16 + fr) * 1024 + h * 64 + kh * 32 + fk]);

    // P = causal-mask(q @ k^T) -> LDS bf16
    {
        bf16x8 kb[4][2];
#pragma unroll
        for (int si = 0; si < 4; ++si)
#pragma unroll
            for (int kh = 0; kh < 2; ++kh)
                kb[si][kh] = *reinterpret_cast<const bf16x8*>(
                    &Kb[(size_t)(tok0 + si * 16 + fr) * 1024 + h * 64 + kh * 32 + fk]);
        f32x4 p[4][4] = {};
        __builtin_amdgcn_s_setprio(1);
#pragma unroll
        for (int mi = 0; mi < 4; ++mi)
#pragma unroll
            for (int si = 0; si < 4; ++si)
#pragma unroll
                for (int kh = 0; kh < 2; ++kh)
                    p[mi][si] = __builtin_amdgcn_mfma_f32_16x16x32_bf16(
                        qa[mi][kh], kb[si][kh], p[mi][si], 0, 0, 0);
        __builtin_amdgcn_s_setprio(0);
#pragma unroll
        for (int mi = 0; mi < 4; ++mi)
#pragma unroll
            for (int si = 0; si < 4; ++si)
#pragma unroll
                for (int r = 0; r < 4; ++r) {
                    int t = mi * 16 + fq * 4 + r;
                    int s = si * 16 + fr;
                    float v = (s <= t) ? p[mi][si][r] : 0.0f;
                    P[t * 72 + s] = f2b(v);
                }
    }
    __syncthreads();

    f32x4 acc[4][4] = {};
    // acc = q @ ST   (STb[de][dk], dk-contiguous)
    {
        const u16* st = STb + (size_t)blk * 4096;
        bf16x8 sb[4][2];
#pragma unroll
        for (int ni = 0; ni < 4; ++ni)
#pragma unroll
            for (int kh = 0; kh < 2; ++kh)
                sb[ni][kh] = *reinterpret_cast<const bf16x8*>(
                    &st[(ni * 16 + fr) * 64 + kh * 32 + fk]);
        __builtin_amdgcn_s_setprio(1);
#pragma unroll
        for (int mi = 0; mi < 4; ++mi)
#pragma unroll
            for (int ni = 0; ni < 4; ++ni)
#pragma unroll
                for (int kh = 0; kh < 2; ++kh)
                    acc[mi][ni] = __builtin_amdgcn_mfma_f32_16x16x32_bf16(
                        qa[mi][kh], sb[ni][kh], acc[mi][ni], 0, 0, 0);
        __builtin_amdgcn_s_setprio(0);
    }
    // acc += P @ v
    {
        const u16* vt = VbT + (size_t)bh * 64 * 2048;
#pragma unroll
        for (int sh = 0; sh < 2; ++sh) {
            bf16x8 pa[4], vb[4];
#pragma unroll
            for (int mi = 0; mi < 4; ++mi)
                pa[mi] = *reinterpret_cast<const bf16x8*>(
                    &P[(mi * 16 + fr) * 72 + sh * 32 + fk]);
#pragma unroll
            for (int ni = 0; ni < 4; ++ni)
                vb[ni] = *reinterpret_cast<const bf16x8*>(
                    &vt[(size_t)(ni * 16 + fr) * 2048 + c * 64 + sh * 32 + fk]);
            __builtin_amdgcn_s_setprio(1);
#pragma unroll
            for (int mi = 0; mi < 4; ++mi)
#pragma unroll
                for (int ni = 0; ni < 4; ++ni)
                    acc[mi][ni] = __builtin_amdgcn_mfma_f32_16x16x32_bf16(
                        pa[mi], vb[ni], acc[mi][ni], 0, 0, 0);
            __builtin_amdgcn_s_setprio(0);
        }
    }
    // write token-major bf16 O
#pragma unroll
    for (int mi = 0; mi < 4; ++mi)
#pragma unroll
        for (int ni = 0; ni < 4; ++ni)
#pragma unroll
            for (int r = 0; r < 4; ++r) {
                int t = tok0 + mi * 16 + fq * 4 + r;
                int n = h * 64 + ni * 16 + fr;
                Ob[(size_t)t * 1024 + n] = f2b(acc[mi][ni][r]);
            }
}

extern "C" void kernel_launch(void* const* d_in, const int* in_sizes, int n_in,
                              void* d_out, int out_size, void* d_ws, size_t ws_size,
                              hipStream_t stream)
{
    (void)in_sizes; (void)n_in; (void)out_size; (void)ws_size;
    const float* x  = (const float*)d_in[0];
    const float* Wq = (const float*)d_in[1];
    const float* bq = (const float*)d_in[2];
    const float* Wk = (const float*)d_in[3];
    const float* bk = (const float*)d_in[4];
    const float* Wv = (const float*)d_in[5];
    const float* bv = (const float*)d_in[6];
    const float* Wo = (const float*)d_in[7];
    const float* bo = (const float*)d_in[8];
    float* out = (float*)d_out;

    char* ws = (char*)d_ws;
    constexpr size_t SZ_ME = (size_t)Mq * Eq * 2;        // 8 MB
    u16*   Qb  = (u16*)  (ws + 0 * SZ_ME);
    u16*   Kb  = (u16*)  (ws + 1 * SZ_ME);
    u16*   KbT = (u16*)  (ws + 2 * SZ_ME);
    u16*   VbT = (u16*)  (ws + 3 * SZ_ME);
    u16*   Ob  = (u16*)  (ws + 4 * SZ_ME);
    u16*   STb = (u16*)  (ws + 5 * SZ_ME);
    u16*   Xb  = (u16*)  (ws + 6 * SZ_ME);
    u16*   Wb0 = (u16*)  (ws + 7 * SZ_ME);               // [Wq|Wk|Wv|Wo] bf16
    u16* Wqkvb = Wb0;
    u16* Wob   = Wb0 + (size_t)3 * Eq * Eq;

    // 1) all bf16 conversions, one launch
    cvt_all_kernel<<<dim3(8192), dim3(256), 0, stream>>>(x, Wq, Wk, Wv, Wo, Xb, Wb0);

    // 2) fused QKV projection (M=4096, N=3072): ring GEMM, 768 blocks x 512 thr
    qkv_ring<<<dim3(768), dim3(512), 0, stream>>>(
        Xb, Wqkvb, bq, bk, bv, Qb, Kb, KbT, VbT);

    // 3) attention: fused chunk-KV+scan, then per-chunk output
    kv_scan_kernel<<<dim3(BH * 4), dim3(64), 0, stream>>>(KbT, VbT, STb);
    attn_kernel<<<dim3(BH * NC), dim3(64), 0, stream>>>(Qb, Kb, VbT, STb, Ob);

    // 4) output projection (M=4096, N=1024): ring GEMM, 512 blocks (2/CU)
    oproj_kernel<<<dim3(512), dim3(256), 0, stream>>>(Ob, Wob, bo, out);
}

// Round 13
// 89.880 us; speedup vs baseline: 1.3789x; 1.1224x over previous
//
#include <hip/hip_runtime.h>
#include <hip/hip_bf16.h>
#include <cmath>

typedef unsigned short u16;
typedef __bf16 bf16x8 __attribute__((ext_vector_type(8)));
typedef float  f32x4  __attribute__((ext_vector_type(4)));
typedef float  f4     __attribute__((ext_vector_type(4)));
typedef u16    us4    __attribute__((ext_vector_type(4)));

#define DEVFN __device__ __forceinline__

static constexpr int Bq = 2, Nq = 2048, Eq = 1024;
static constexpr int Mq = Bq * Nq;        // 4096 tokens
static constexpr int CHK = 64;            // attention chunk
static constexpr int NC  = Nq / CHK;      // 32 chunks
static constexpr int BH  = Bq * 16;       // 32

DEVFN u16 f2b(float f) {                  // f32 -> bf16 (RNE), finite inputs
    union { float f; unsigned int u; } x; x.f = f;
    unsigned int r = x.u + 0x7fffu + ((x.u >> 16) & 1u);
    return (u16)(r >> 16);
}
DEVFN float b2f(u16 v) {
    union { unsigned int u; float f; } x; x.u = ((unsigned int)v) << 16; return x.f;
}

DEVFN void gl_lds16(const u16* g, u16* l) {  // async 16B global->LDS (dest: wave base + lane*16)
    __builtin_amdgcn_global_load_lds(
        (const __attribute__((address_space(1))) unsigned int*)(g),
        (__attribute__((address_space(3))) unsigned int*)(l),
        16, 0, 0);
}

// ---------------- all f32 -> bf16 converts in ONE launch ----------------
__global__ __launch_bounds__(256)
void cvt_all_kernel(const float* __restrict__ x,
                    const float* __restrict__ w0, const float* __restrict__ w1,
                    const float* __restrict__ w2, const float* __restrict__ w3,
                    u16* __restrict__ Xb, u16* __restrict__ Wb)
{
    const int blk = blockIdx.x;
    const float* s; u16* d; int i;
    if (blk < 4096) {
        i = blk * 256 + threadIdx.x;  s = x;  d = Xb;
    } else {
        const int wsel = (blk - 4096) >> 10;
        i = ((blk - 4096) & 1023) * 256 + threadIdx.x;
        s = (wsel == 0) ? w0 : (wsel == 1) ? w1 : (wsel == 2) ? w2 : w3;
        d = Wb + (size_t)wsel * (Eq * Eq);
    }
    f4 v = *reinterpret_cast<const f4*>(&s[(size_t)i * 4]);
    us4 p; p[0] = f2b(v[0]); p[1] = f2b(v[1]); p[2] = f2b(v[2]); p[3] = f2b(v[3]);
    *reinterpret_cast<us4*>(&d[(size_t)i * 4]) = p;
}

// ======== QKV ring GEMM: 128x128 tile, 8 waves (32x64 each), BK=32, ring-3 ========
// R10-exact (best measured: 43.2 us). 512 thr -> 24 waves/CU; 2 gl_lds/tile;
// steady vmcnt(2); swizzle sigma(row)=(row>>1)&3 both sides (0 conflicts).
__global__ __launch_bounds__(512, 4)
void qkv_ring(const u16* __restrict__ X, const u16* __restrict__ W,
              const float* __restrict__ b0, const float* __restrict__ b1,
              const float* __restrict__ b2,
              u16* __restrict__ Qb, u16* __restrict__ Kb, u16* __restrict__ KbT,
              u16* __restrict__ VbT)
{
    constexpr int BUFU = 8192;                // 16KB: A 4096 u16 | B 4096 u16
    __shared__ u16 lds[3 * BUFU];             // 48KB -> 3 blocks/CU
    const int tid = threadIdx.x, wid = tid >> 6, lane = tid & 63;
    const int wr = (wid >> 1) * 32, wc = (wid & 1) * 64;   // wave: 32 rows x 64 cols
    const int fr = lane & 15, fq = lane >> 4;

    const int bid = blockIdx.x;               // grid 768 = 8 * 96 (XCD-bijective)
    const int fid = (bid & 7) * 96 + (bid >> 3);
    const int bx = fid % 24, by = fid / 24;
    const int m0 = by * 128, n0 = bx * 128;

    // staging: one round = 512 thr x 16B = 128 rows x 4 slots (full matrix)
    const int row0 = tid >> 2;
    const int sc   = ((tid & 3) ^ ((row0 >> 1) & 3)) * 8;   // swizzled source slot
    const u16* gA = X + (size_t)(m0 + row0) * 1024 + sc;
    const u16* gB = W + (size_t)(n0 + row0) * 1024 + sc;
    const int dw = wid * 512;                 // wave-uniform dest piece (1KB/wave)

    // fragment reads: same involution on read side
    const int fsw = (fq ^ ((fr >> 1) & 3)) << 3;
    int aoff[2], boff[4];
#pragma unroll
    for (int mi = 0; mi < 2; ++mi) aoff[mi] = (wr + mi * 16 + fr) * 32 + fsw;
#pragma unroll
    for (int ni = 0; ni < 4; ++ni) boff[ni] = 4096 + (wc + ni * 16 + fr) * 32 + fsw;

#define STAGE(kt, bs) do { u16* _b = lds + (bs) * BUFU;                        \
        gl_lds16(gA + (kt) * 32, _b + dw);                                     \
        gl_lds16(gB + (kt) * 32, _b + 4096 + dw); } while (0)

    // prologue: tiles 0,1 staged (4 loads); wait tile0 (tile1's 2 stay in flight)
    STAGE(0, 0);
    STAGE(1, 1);
    asm volatile("s_waitcnt vmcnt(2)" ::: "memory");
    __builtin_amdgcn_sched_barrier(0);
    __builtin_amdgcn_s_barrier();

    f32x4 acc[2][4] = {};
    int cb = 0, sb = 2;

    for (int t = 0; t < 32; ++t) {
        if (t + 2 < 32) STAGE(t + 2, sb);
        const u16* buf = lds + cb * BUFU;
        bf16x8 af[2], bfv[4];
#pragma unroll
        for (int mi = 0; mi < 2; ++mi)
            af[mi] = *reinterpret_cast<const bf16x8*>(&buf[aoff[mi]]);
#pragma unroll
        for (int ni = 0; ni < 4; ++ni)
            bfv[ni] = *reinterpret_cast<const bf16x8*>(&buf[boff[ni]]);
        __builtin_amdgcn_s_setprio(1);
#pragma unroll
        for (int mi = 0; mi < 2; ++mi)
#pragma unroll
            for (int ni = 0; ni < 4; ++ni)
                acc[mi][ni] = __builtin_amdgcn_mfma_f32_16x16x32_bf16(
                    af[mi], bfv[ni], acc[mi][ni], 0, 0, 0);
        __builtin_amdgcn_s_setprio(0);
        // tile boundary: t+1 landed; keep t+2's 2 loads in flight
        if (t < 30)       asm volatile("s_waitcnt vmcnt(2)" ::: "memory");
        else if (t == 30) asm volatile("s_waitcnt vmcnt(0)" ::: "memory");
        __builtin_amdgcn_sched_barrier(0);
        __builtin_amdgcn_s_barrier();
        cb = (cb == 2) ? 0 : cb + 1;
        sb = (sb == 2) ? 0 : sb + 1;
    }
#undef STAGE

    const int nw  = n0 + wc;                           // 64-aligned, seg-uniform
    const int seg = nw >> 10;                          // 0=q 1=k 2=v
    const float* bp = (seg == 0) ? b0 : (seg == 1) ? b1 : b2;
#pragma unroll
    for (int mi = 0; mi < 2; ++mi)
#pragma unroll
        for (int ni = 0; ni < 4; ++ni) {
            const int nl    = (nw & 1023) + ni * 16 + fr;
            const int mbase = m0 + wr + mi * 16 + fq * 4;
            const float bn  = bp[nl];
            float vr[4];
#pragma unroll
            for (int r = 0; r < 4; ++r) {
                float v = acc[mi][ni][r] + bn;
                if (seg < 2) v = (v > 0.f) ? (v + 1.f) : __expf(v);  // elu+1
                vr[r] = v;
            }
            if (seg == 0) {
#pragma unroll
                for (int r = 0; r < 4; ++r)
                    Qb[(size_t)(mbase + r) * 1024 + nl] = f2b(vr[r]);
            } else {
                us4 pk;
#pragma unroll
                for (int r = 0; r < 4; ++r) pk[r] = f2b(vr[r]);
                const int bb = mbase >> 11, nt = mbase & 2047;
                const int hh = nl >> 6,     dd = nl & 63;
                u16* T = (seg == 1) ? KbT : VbT;
                *reinterpret_cast<us4*>(
                    &T[((size_t)(bb * 16 + hh) * 64 + dd) * 2048 + nt]) = pk;
                if (seg == 1) {
#pragma unroll
                    for (int r = 0; r < 4; ++r)
                        Kb[(size_t)(mbase + r) * 1024 + nl] = f2b(vr[r]);
                }
            }
        }
}

// ======== O-proj: 64x128 tile, 4 waves, BK=32, ring-3, dup-free (R8/R10, verified) ========
__global__ __launch_bounds__(256)
void oproj_kernel(const u16* __restrict__ X, const u16* __restrict__ W,
                  const float* __restrict__ b0, float* __restrict__ outF)
{
    constexpr int BUFU = (64 + 128) * 32;     // 6144 u16 = 12KB per buffer
    __shared__ u16 lds[3 * BUFU];             // 36KB
    const int tid = threadIdx.x, wid = tid >> 6, lane = tid & 63;
    const int wr = (wid >> 1) * 32, wc = (wid & 1) * 64;
    const int fr = lane & 15, fq = lane >> 4;

    const int bid = blockIdx.x;               // grid 512 = 8 * 64
    const int fid = (bid & 7) * 64 + (bid >> 3);
    const int bx = fid & 7, by = fid >> 3;
    const int m0 = by * 64, n0 = bx * 128;

    const int ra = tid >> 2;
    const int sc = ((tid & 3) ^ ((tid >> 3) & 3)) * 8;
    const u16* gA = X + (size_t)(m0 + ra) * 1024 + sc;
    const u16* gB = W + (size_t)(n0 + ra) * 1024 + sc;
    const int dw = wid * 512;

    const int fsw = (fq ^ ((fr >> 1) & 3)) << 3;
    int aoff[2], boff[4];
#pragma unroll
    for (int mi = 0; mi < 2; ++mi) aoff[mi] = (wr + mi * 16 + fr) * 32 + fsw;
#pragma unroll
    for (int ni = 0; ni < 4; ++ni) boff[ni] = 2048 + (wc + ni * 16 + fr) * 32 + fsw;

#define STAGE(kt, bs) do { u16* _b = lds + (bs) * BUFU;                          \
        gl_lds16(gA + (kt) * 32,             _b + dw);                           \
        gl_lds16(gB + (kt) * 32,             _b + 2048 + dw);                    \
        gl_lds16(gB + (kt) * 32 + 64 * 1024, _b + 4096 + dw); } while (0)

    STAGE(0, 0);
    STAGE(1, 1);
    asm volatile("s_waitcnt vmcnt(3)" ::: "memory");
    __builtin_amdgcn_sched_barrier(0);
    __builtin_amdgcn_s_barrier();

    f32x4 acc[2][4] = {};
    int cb = 0, sb = 2;

    for (int t = 0; t < 32; ++t) {
        if (t + 2 < 32) STAGE(t + 2, sb);
        const u16* buf = lds + cb * BUFU;
        bf16x8 af[2], bfv[4];
#pragma unroll
        for (int mi = 0; mi < 2; ++mi)
            af[mi] = *reinterpret_cast<const bf16x8*>(&buf[aoff[mi]]);
#pragma unroll
        for (int ni = 0; ni < 4; ++ni)
            bfv[ni] = *reinterpret_cast<const bf16x8*>(&buf[boff[ni]]);
        __builtin_amdgcn_s_setprio(1);
#pragma unroll
        for (int mi = 0; mi < 2; ++mi)
#pragma unroll
            for (int ni = 0; ni < 4; ++ni)
                acc[mi][ni] = __builtin_amdgcn_mfma_f32_16x16x32_bf16(
                    af[mi], bfv[ni], acc[mi][ni], 0, 0, 0);
        __builtin_amdgcn_s_setprio(0);
        if (t < 30)       asm volatile("s_waitcnt vmcnt(3)" ::: "memory");
        else if (t == 30) asm volatile("s_waitcnt vmcnt(0)" ::: "memory");
        __builtin_amdgcn_sched_barrier(0);
        __builtin_amdgcn_s_barrier();
        cb = (cb == 2) ? 0 : cb + 1;
        sb = (sb == 2) ? 0 : sb + 1;
    }
#undef STAGE

#pragma unroll
    for (int mi = 0; mi < 2; ++mi)
#pragma unroll
        for (int ni = 0; ni < 4; ++ni) {
            const int n     = n0 + wc + ni * 16 + fr;
            const int mbase = m0 + wr + mi * 16 + fq * 4;
            const float bn  = b0[n];
#pragma unroll
            for (int r = 0; r < 4; ++r)
                outF[(size_t)(mbase + r) * 1024 + n] = acc[mi][ni][r] + bn;
        }
}

// ---------------- per-chunk KV^T = v^T @ k: KVT[de][dk], bf16 out ----------------
__global__ __launch_bounds__(64)
void chunk_kv_kernel(const u16* __restrict__ KbT, const u16* __restrict__ VbT,
                     u16* __restrict__ KVT)
{
    const int blk = blockIdx.x;          // bh*NC + c
    const int bh = blk >> 5, c = blk & 31;
    const int lane = threadIdx.x;
    const int fr = lane & 15, fq = lane >> 4, fk = fq * 8;
    const u16* kt = KbT + (size_t)bh * 64 * 2048;
    const u16* vt = VbT + (size_t)bh * 64 * 2048;

    bf16x8 a[4][2], b[4][2];             // a = V rows (de), b = K rows (dk)
#pragma unroll
    for (int mi = 0; mi < 4; ++mi)
#pragma unroll
        for (int kh = 0; kh < 2; ++kh)
            a[mi][kh] = *reinterpret_cast<const bf16x8*>(
                &vt[(size_t)(mi * 16 + fr) * 2048 + c * 64 + kh * 32 + fk]);
#pragma unroll
    for (int ni = 0; ni < 4; ++ni)
#pragma unroll
        for (int kh = 0; kh < 2; ++kh)
            b[ni][kh] = *reinterpret_cast<const bf16x8*>(
                &kt[(size_t)(ni * 16 + fr) * 2048 + c * 64 + kh * 32 + fk]);

    f32x4 acc[4][4] = {};
    __builtin_amdgcn_s_setprio(1);
#pragma unroll
    for (int mi = 0; mi < 4; ++mi)
#pragma unroll
        for (int ni = 0; ni < 4; ++ni)
#pragma unroll
            for (int kh = 0; kh < 2; ++kh)
                acc[mi][ni] = __builtin_amdgcn_mfma_f32_16x16x32_bf16(
                    a[mi][kh], b[ni][kh], acc[mi][ni], 0, 0, 0);
    __builtin_amdgcn_s_setprio(0);

    u16* out = KVT + (size_t)blk * 4096;   // [de][dk] bf16
#pragma unroll
    for (int mi = 0; mi < 4; ++mi)
#pragma unroll
        for (int ni = 0; ni < 4; ++ni)
#pragma unroll
            for (int r = 0; r < 4; ++r)
                out[(mi * 16 + fq * 4 + r) * 64 + ni * 16 + fr] = f2b(acc[mi][ni][r]);
}

// ---------------- elementwise exclusive scan over chunks (bf16 in/out) ----------------
__global__ __launch_bounds__(256)
void scan_kernel(const u16* __restrict__ KVT, u16* __restrict__ STb)
{
    const int bh = blockIdx.x >> 4, sl = blockIdx.x & 15;
    const int el = sl * 256 + threadIdx.x;              // element of [de][dk]
    const u16* src = KVT + (size_t)bh * NC * 4096 + el;
    u16*      dst  = STb + (size_t)bh * NC * 4096 + el;
    float run = 0.f;
#pragma unroll 4
    for (int c = 0; c < NC; ++c) {
        dst[(size_t)c * 4096] = f2b(run);               // exclusive prefix
        run += b2f(src[(size_t)c * 4096]);
    }
}

// ---------------- per-chunk attention output ----------------
__global__ __launch_bounds__(64)
void attn_kernel(const u16* __restrict__ Qb, const u16* __restrict__ Kb,
                 const u16* __restrict__ VbT, const u16* __restrict__ STb,
                 u16* __restrict__ Ob)
{
    __shared__ u16 P[64 * 72];   // stride 72 u16 = 144B: 16B-aligned, 2-way banks
    const int blk = blockIdx.x;
    const int bh = blk >> 5, c = blk & 31;
    const int b = bh >> 4, h = bh & 15;
    const int lane = threadIdx.x;
    const int fr = lane & 15, fq = lane >> 4, fk = fq * 8;
    const int tok0 = b * 2048 + c * 64;

    bf16x8 qa[4][2];
#pragma unroll
    for (int mi = 0; mi < 4; ++mi)
#pragma unroll
        for (int kh = 0; kh < 2; ++kh)
            qa[mi][kh] = *reinterpret_cast<const bf16x8*>(
                &Qb[(size_t)(tok0 + mi * 16 + fr) * 1024 + h * 64 + kh * 32 + fk]);

    // P = causal-mask(q @ k^T) -> LDS bf16
    {
        bf16x8 kb[4][2];
#pragma unroll
        for (int si = 0; si < 4; ++si)
#pragma unroll
            for (int kh = 0; kh < 2; ++kh)
                kb[si][kh] = *reinterpret_cast<const bf16x8*>(
                    &Kb[(size_t)(tok0 + si * 16 + fr) * 1024 + h * 64 + kh * 32 + fk]);
        f32x4 p[4][4] = {};
        __builtin_amdgcn_s_setprio(1);
#pragma unroll
        for (int mi = 0; mi < 4; ++mi)
#pragma unroll
            for (int si = 0; si < 4; ++si)
#pragma unroll
                for (int kh = 0; kh < 2; ++kh)
                    p[mi][si] = __builtin_amdgcn_mfma_f32_16x16x32_bf16(
                        qa[mi][kh], kb[si][kh], p[mi][si], 0, 0, 0);
        __builtin_amdgcn_s_setprio(0);
#pragma unroll
        for (int mi = 0; mi < 4; ++mi)
#pragma unroll
            for (int si = 0; si < 4; ++si)
#pragma unroll
                for (int r = 0; r < 4; ++r) {
                    int t = mi * 16 + fq * 4 + r;
                    int s = si * 16 + fr;
                    float v = (s <= t) ? p[mi][si][r] : 0.0f;
                    P[t * 72 + s] = f2b(v);
                }
    }
    __syncthreads();

    f32x4 acc[4][4] = {};
    // acc = q @ ST   (STb[de][dk], dk-contiguous)
    {
        const u16* st = STb + (size_t)blk * 4096;
        bf16x8 sb[4][2];
#pragma unroll
        for (int ni = 0; ni < 4; ++ni)
#pragma unroll
            for (int kh = 0; kh < 2; ++kh)
                sb[ni][kh] = *reinterpret_cast<const bf16x8*>(
                    &st[(ni * 16 + fr) * 64 + kh * 32 + fk]);
        __builtin_amdgcn_s_setprio(1);
#pragma unroll
        for (int mi = 0; mi < 4; ++mi)
#pragma unroll
            for (int ni = 0; ni < 4; ++ni)
#pragma unroll
                for (int kh = 0; kh < 2; ++kh)
                    acc[mi][ni] = __builtin_amdgcn_mfma_f32_16x16x32_bf16(
                        qa[mi][kh], sb[ni][kh], acc[mi][ni], 0, 0, 0);
        __builtin_amdgcn_s_setprio(0);
    }
    // acc += P @ v
    {
        const u16* vt = VbT + (size_t)bh * 64 * 2048;
#pragma unroll
        for (int sh = 0; sh < 2; ++sh) {
            bf16x8 pa[4], vb[4];
#pragma unroll
            for (int mi = 0; mi < 4; ++mi)
                pa[mi] = *reinterpret_cast<const bf16x8*>(
                    &P[(mi * 16 + fr) * 72 + sh * 32 + fk]);
#pragma unroll
            for (int ni = 0; ni < 4; ++ni)
                vb[ni] = *reinterpret_cast<const bf16x8*>(
                    &vt[(size_t)(ni * 16 + fr) * 2048 + c * 64 + sh * 32 + fk]);
            __builtin_amdgcn_s_setprio(1);
#pragma unroll
            for (int mi = 0; mi < 4; ++mi)
#pragma unroll
                for (int ni = 0; ni < 4; ++ni)
                    acc[mi][ni] = __builtin_amdgcn_mfma_f32_16x16x32_bf16(
                        pa[mi], vb[ni], acc[mi][ni], 0, 0, 0);
            __builtin_amdgcn_s_setprio(0);
        }
    }
    // write token-major bf16 O
#pragma unroll
    for (int mi = 0; mi < 4; ++mi)
#pragma unroll
        for (int ni = 0; ni < 4; ++ni)
#pragma unroll
            for (int r = 0; r < 4; ++r) {
                int t = tok0 + mi * 16 + fq * 4 + r;
                int n = h * 64 + ni * 16 + fr;
                Ob[(size_t)t * 1024 + n] = f2b(acc[mi][ni][r]);
            }
}

extern "C" void kernel_launch(void* const* d_in, const int* in_sizes, int n_in,
                              void* d_out, int out_size, void* d_ws, size_t ws_size,
                              hipStream_t stream)
{
    (void)in_sizes; (void)n_in; (void)out_size; (void)ws_size;
    const float* x  = (const float*)d_in[0];
    const float* Wq = (const float*)d_in[1];
    const float* bq = (const float*)d_in[2];
    const float* Wk = (const float*)d_in[3];
    const float* bk = (const float*)d_in[4];
    const float* Wv = (const float*)d_in[5];
    const float* bv = (const float*)d_in[6];
    const float* Wo = (const float*)d_in[7];
    const float* bo = (const float*)d_in[8];
    float* out = (float*)d_out;

    char* ws = (char*)d_ws;
    constexpr size_t SZ_ME = (size_t)Mq * Eq * 2;        // 8 MB
    u16*   Qb  = (u16*)  (ws + 0 * SZ_ME);
    u16*   Kb  = (u16*)  (ws + 1 * SZ_ME);
    u16*   KbT = (u16*)  (ws + 2 * SZ_ME);
    u16*   VbT = (u16*)  (ws + 3 * SZ_ME);
    u16*   Ob  = (u16*)  (ws + 4 * SZ_ME);
    u16*   KVT = (u16*)  (ws + 5 * SZ_ME);               // 8 MB bf16
    u16*   STb = (u16*)  (ws + 6 * SZ_ME);
    u16*   Xb  = (u16*)  (ws + 7 * SZ_ME);
    u16*   Wb0 = (u16*)  (ws + 8 * SZ_ME);               // [Wq|Wk|Wv|Wo] bf16
    u16* Wqkvb = Wb0;
    u16* Wob   = Wb0 + (size_t)3 * Eq * Eq;

    // 1) all bf16 conversions, one launch
    cvt_all_kernel<<<dim3(8192), dim3(256), 0, stream>>>(x, Wq, Wk, Wv, Wo, Xb, Wb0);

    // 2) fused QKV projection (M=4096, N=3072): ring GEMM, 768 blocks x 512 thr
    qkv_ring<<<dim3(768), dim3(512), 0, stream>>>(
        Xb, Wqkvb, bq, bk, bv, Qb, Kb, KbT, VbT);

    // 3) attention
    chunk_kv_kernel<<<dim3(BH * NC), dim3(64), 0, stream>>>(KbT, VbT, KVT);
    scan_kernel<<<dim3(BH * 16), dim3(256), 0, stream>>>(KVT, STb);
    attn_kernel<<<dim3(BH * NC), dim3(64), 0, stream>>>(Qb, Kb, VbT, STb, Ob);

    // 4) output projection (M=4096, N=1024): ring GEMM, 512 blocks (2/CU)
    oproj_kernel<<<dim3(512), dim3(256), 0, stream>>>(Ob, Wob, bo, out);
}

// Round 14
// 89.878 us; speedup vs baseline: 1.3789x; 1.0000x over previous
//
#include <hip/hip_runtime.h>
#include <hip/hip_bf16.h>
#include <cmath>

typedef unsigned short u16;
typedef __bf16 bf16x8 __attribute__((ext_vector_type(8)));
typedef float  f32x4  __attribute__((ext_vector_type(4)));
typedef float  f4     __attribute__((ext_vector_type(4)));
typedef u16    us4    __attribute__((ext_vector_type(4)));

#define DEVFN __device__ __forceinline__

static constexpr int Bq = 2, Nq = 2048, Eq = 1024;
static constexpr int Mq = Bq * Nq;        // 4096 tokens
static constexpr int CHK = 64;            // attention chunk
static constexpr int NC  = Nq / CHK;      // 32 chunks
static constexpr int BH  = Bq * 16;       // 32

DEVFN u16 f2b(float f) {                  // f32 -> bf16 (RNE), finite inputs
    union { float f; unsigned int u; } x; x.f = f;
    unsigned int r = x.u + 0x7fffu + ((x.u >> 16) & 1u);
    return (u16)(r >> 16);
}
DEVFN float b2f(u16 v) {
    union { unsigned int u; float f; } x; x.u = ((unsigned int)v) << 16; return x.f;
}

DEVFN void gl_lds16(const u16* g, u16* l) {  // async 16B global->LDS (dest: wave base + lane*16)
    __builtin_amdgcn_global_load_lds(
        (const __attribute__((address_space(1))) unsigned int*)(g),
        (__attribute__((address_space(3))) unsigned int*)(l),
        16, 0, 0);
}

// ---------------- all f32 -> bf16 converts in ONE launch ----------------
__global__ __launch_bounds__(256)
void cvt_all_kernel(const float* __restrict__ x,
                    const float* __restrict__ w0, const float* __restrict__ w1,
                    const float* __restrict__ w2, const float* __restrict__ w3,
                    u16* __restrict__ Xb, u16* __restrict__ Wb)
{
    const int blk = blockIdx.x;
    const float* s; u16* d; int i;
    if (blk < 4096) {
        i = blk * 256 + threadIdx.x;  s = x;  d = Xb;
    } else {
        const int wsel = (blk - 4096) >> 10;
        i = ((blk - 4096) & 1023) * 256 + threadIdx.x;
        s = (wsel == 0) ? w0 : (wsel == 1) ? w1 : (wsel == 2) ? w2 : w3;
        d = Wb + (size_t)wsel * (Eq * Eq);
    }
    f4 v = *reinterpret_cast<const f4*>(&s[(size_t)i * 4]);
    us4 p; p[0] = f2b(v[0]); p[1] = f2b(v[1]); p[2] = f2b(v[2]); p[3] = f2b(v[3]);
    *reinterpret_cast<us4*>(&d[(size_t)i * 4]) = p;
}

// ======== QKV ring GEMM: 128x128 tile, 8 waves (32x64 each), BK=32, ring-3 ========
// R10-exact (best measured: 42.6 us). 512 thr -> 24 waves/CU; 2 gl_lds/tile;
// steady vmcnt(2); swizzle sigma(row)=(row>>1)&3 both sides (0 conflicts).
__global__ __launch_bounds__(512, 4)
void qkv_ring(const u16* __restrict__ X, const u16* __restrict__ W,
              const float* __restrict__ b0, const float* __restrict__ b1,
              const float* __restrict__ b2,
              u16* __restrict__ Qb, u16* __restrict__ Kb, u16* __restrict__ KbT,
              u16* __restrict__ VbT)
{
    constexpr int BUFU = 8192;                // 16KB: A 4096 u16 | B 4096 u16
    __shared__ u16 lds[3 * BUFU];             // 48KB -> 3 blocks/CU
    const int tid = threadIdx.x, wid = tid >> 6, lane = tid & 63;
    const int wr = (wid >> 1) * 32, wc = (wid & 1) * 64;   // wave: 32 rows x 64 cols
    const int fr = lane & 15, fq = lane >> 4;

    const int bid = blockIdx.x;               // grid 768 = 8 * 96 (XCD-bijective)
    const int fid = (bid & 7) * 96 + (bid >> 3);
    const int bx = fid % 24, by = fid / 24;
    const int m0 = by * 128, n0 = bx * 128;

    // staging: one round = 512 thr x 16B = 128 rows x 4 slots (full matrix)
    const int row0 = tid >> 2;
    const int sc   = ((tid & 3) ^ ((row0 >> 1) & 3)) * 8;   // swizzled source slot
    const u16* gA = X + (size_t)(m0 + row0) * 1024 + sc;
    const u16* gB = W + (size_t)(n0 + row0) * 1024 + sc;
    const int dw = wid * 512;                 // wave-uniform dest piece (1KB/wave)

    // fragment reads: same involution on read side
    const int fsw = (fq ^ ((fr >> 1) & 3)) << 3;
    int aoff[2], boff[4];
#pragma unroll
    for (int mi = 0; mi < 2; ++mi) aoff[mi] = (wr + mi * 16 + fr) * 32 + fsw;
#pragma unroll
    for (int ni = 0; ni < 4; ++ni) boff[ni] = 4096 + (wc + ni * 16 + fr) * 32 + fsw;

#define STAGE(kt, bs) do { u16* _b = lds + (bs) * BUFU;                        \
        gl_lds16(gA + (kt) * 32, _b + dw);                                     \
        gl_lds16(gB + (kt) * 32, _b + 4096 + dw); } while (0)

    // prologue: tiles 0,1 staged (4 loads); wait tile0 (tile1's 2 stay in flight)
    STAGE(0, 0);
    STAGE(1, 1);
    asm volatile("s_waitcnt vmcnt(2)" ::: "memory");
    __builtin_amdgcn_sched_barrier(0);
    __builtin_amdgcn_s_barrier();

    f32x4 acc[2][4] = {};
    int cb = 0, sb = 2;

    for (int t = 0; t < 32; ++t) {
        if (t + 2 < 32) STAGE(t + 2, sb);
        const u16* buf = lds + cb * BUFU;
        bf16x8 af[2], bfv[4];
#pragma unroll
        for (int mi = 0; mi < 2; ++mi)
            af[mi] = *reinterpret_cast<const bf16x8*>(&buf[aoff[mi]]);
#pragma unroll
        for (int ni = 0; ni < 4; ++ni)
            bfv[ni] = *reinterpret_cast<const bf16x8*>(&buf[boff[ni]]);
        __builtin_amdgcn_s_setprio(1);
#pragma unroll
        for (int mi = 0; mi < 2; ++mi)
#pragma unroll
            for (int ni = 0; ni < 4; ++ni)
                acc[mi][ni] = __builtin_amdgcn_mfma_f32_16x16x32_bf16(
                    af[mi], bfv[ni], acc[mi][ni], 0, 0, 0);
        __builtin_amdgcn_s_setprio(0);
        // tile boundary: t+1 landed; keep t+2's 2 loads in flight
        if (t < 30)       asm volatile("s_waitcnt vmcnt(2)" ::: "memory");
        else if (t == 30) asm volatile("s_waitcnt vmcnt(0)" ::: "memory");
        __builtin_amdgcn_sched_barrier(0);
        __builtin_amdgcn_s_barrier();
        cb = (cb == 2) ? 0 : cb + 1;
        sb = (sb == 2) ? 0 : sb + 1;
    }
#undef STAGE

    const int nw  = n0 + wc;                           // 64-aligned, seg-uniform
    const int seg = nw >> 10;                          // 0=q 1=k 2=v
    const float* bp = (seg == 0) ? b0 : (seg == 1) ? b1 : b2;
#pragma unroll
    for (int mi = 0; mi < 2; ++mi)
#pragma unroll
        for (int ni = 0; ni < 4; ++ni) {
            const int nl    = (nw & 1023) + ni * 16 + fr;
            const int mbase = m0 + wr + mi * 16 + fq * 4;
            const float bn  = bp[nl];
            float vr[4];
#pragma unroll
            for (int r = 0; r < 4; ++r) {
                float v = acc[mi][ni][r] + bn;
                if (seg < 2) v = (v > 0.f) ? (v + 1.f) : __expf(v);  // elu+1
                vr[r] = v;
            }
            if (seg == 0) {
#pragma unroll
                for (int r = 0; r < 4; ++r)
                    Qb[(size_t)(mbase + r) * 1024 + nl] = f2b(vr[r]);
            } else {
                us4 pk;
#pragma unroll
                for (int r = 0; r < 4; ++r) pk[r] = f2b(vr[r]);
                const int bb = mbase >> 11, nt = mbase & 2047;
                const int hh = nl >> 6,     dd = nl & 63;
                u16* T = (seg == 1) ? KbT : VbT;
                *reinterpret_cast<us4*>(
                    &T[((size_t)(bb * 16 + hh) * 64 + dd) * 2048 + nt]) = pk;
                if (seg == 1) {
#pragma unroll
                    for (int r = 0; r < 4; ++r)
                        Kb[(size_t)(mbase + r) * 1024 + nl] = f2b(vr[r]);
                }
            }
        }
}

// ======== O-proj: 64x128 tile, 4 waves, BK=32, ring-3, dup-free (verified) ========
__global__ __launch_bounds__(256)
void oproj_kernel(const u16* __restrict__ X, const u16* __restrict__ W,
                  const float* __restrict__ b0, float* __restrict__ outF)
{
    constexpr int BUFU = (64 + 128) * 32;     // 6144 u16 = 12KB per buffer
    __shared__ u16 lds[3 * BUFU];             // 36KB
    const int tid = threadIdx.x, wid = tid >> 6, lane = tid & 63;
    const int wr = (wid >> 1) * 32, wc = (wid & 1) * 64;
    const int fr = lane & 15, fq = lane >> 4;

    const int bid = blockIdx.x;               // grid 512 = 8 * 64
    const int fid = (bid & 7) * 64 + (bid >> 3);
    const int bx = fid & 7, by = fid >> 3;
    const int m0 = by * 64, n0 = bx * 128;

    const int ra = tid >> 2;
    const int sc = ((tid & 3) ^ ((tid >> 3) & 3)) * 8;
    const u16* gA = X + (size_t)(m0 + ra) * 1024 + sc;
    const u16* gB = W + (size_t)(n0 + ra) * 1024 + sc;
    const int dw = wid * 512;

    const int fsw = (fq ^ ((fr >> 1) & 3)) << 3;
    int aoff[2], boff[4];
#pragma unroll
    for (int mi = 0; mi < 2; ++mi) aoff[mi] = (wr + mi * 16 + fr) * 32 + fsw;
#pragma unroll
    for (int ni = 0; ni < 4; ++ni) boff[ni] = 2048 + (wc + ni * 16 + fr) * 32 + fsw;

#define STAGE(kt, bs) do { u16* _b = lds + (bs) * BUFU;                          \
        gl_lds16(gA + (kt) * 32,             _b + dw);                           \
        gl_lds16(gB + (kt) * 32,             _b + 2048 + dw);                    \
        gl_lds16(gB + (kt) * 32 + 64 * 1024, _b + 4096 + dw); } while (0)

    STAGE(0, 0);
    STAGE(1, 1);
    asm volatile("s_waitcnt vmcnt(3)" ::: "memory");
    __builtin_amdgcn_sched_barrier(0);
    __builtin_amdgcn_s_barrier();

    f32x4 acc[2][4] = {};
    int cb = 0, sb = 2;

    for (int t = 0; t < 32; ++t) {
        if (t + 2 < 32) STAGE(t + 2, sb);
        const u16* buf = lds + cb * BUFU;
        bf16x8 af[2], bfv[4];
#pragma unroll
        for (int mi = 0; mi < 2; ++mi)
            af[mi] = *reinterpret_cast<const bf16x8*>(&buf[aoff[mi]]);
#pragma unroll
        for (int ni = 0; ni < 4; ++ni)
            bfv[ni] = *reinterpret_cast<const bf16x8*>(&buf[boff[ni]]);
        __builtin_amdgcn_s_setprio(1);
#pragma unroll
        for (int mi = 0; mi < 2; ++mi)
#pragma unroll
            for (int ni = 0; ni < 4; ++ni)
                acc[mi][ni] = __builtin_amdgcn_mfma_f32_16x16x32_bf16(
                    af[mi], bfv[ni], acc[mi][ni], 0, 0, 0);
        __builtin_amdgcn_s_setprio(0);
        if (t < 30)       asm volatile("s_waitcnt vmcnt(3)" ::: "memory");
        else if (t == 30) asm volatile("s_waitcnt vmcnt(0)" ::: "memory");
        __builtin_amdgcn_sched_barrier(0);
        __builtin_amdgcn_s_barrier();
        cb = (cb == 2) ? 0 : cb + 1;
        sb = (sb == 2) ? 0 : sb + 1;
    }
#undef STAGE

#pragma unroll
    for (int mi = 0; mi < 2; ++mi)
#pragma unroll
        for (int ni = 0; ni < 4; ++ni) {
            const int n     = n0 + wc + ni * 16 + fr;
            const int mbase = m0 + wr + mi * 16 + fq * 4;
            const float bn  = b0[n];
#pragma unroll
            for (int r = 0; r < 4; ++r)
                outF[(size_t)(mbase + r) * 1024 + n] = acc[mi][ni][r] + bn;
        }
}

// ======== per-chunk KV^T = v^T @ k, ni-split: 2048 one-wave blocks (8 waves/CU) ========
__global__ __launch_bounds__(64)
void chunk_kv_kernel(const u16* __restrict__ KbT, const u16* __restrict__ VbT,
                     u16* __restrict__ KVT)
{
    const int blk = blockIdx.x;          // (bh*NC + c)*2 + nh
    const int nh = blk & 1;
    const int bc = blk >> 1;
    const int bh = bc >> 5, c = bc & 31;
    const int lane = threadIdx.x;
    const int fr = lane & 15, fq = lane >> 4, fk = fq * 8;
    const u16* kt = KbT + (size_t)bh * 64 * 2048;
    const u16* vt = VbT + (size_t)bh * 64 * 2048;

    bf16x8 a[4][2], b[2][2];             // a = V rows (de, all), b = K rows (ni-half)
#pragma unroll
    for (int mi = 0; mi < 4; ++mi)
#pragma unroll
        for (int kh = 0; kh < 2; ++kh)
            a[mi][kh] = *reinterpret_cast<const bf16x8*>(
                &vt[(size_t)(mi * 16 + fr) * 2048 + c * 64 + kh * 32 + fk]);
#pragma unroll
    for (int ni = 0; ni < 2; ++ni)
#pragma unroll
        for (int kh = 0; kh < 2; ++kh)
            b[ni][kh] = *reinterpret_cast<const bf16x8*>(
                &kt[(size_t)((nh * 2 + ni) * 16 + fr) * 2048 + c * 64 + kh * 32 + fk]);

    f32x4 acc[4][2] = {};
    __builtin_amdgcn_s_setprio(1);
#pragma unroll
    for (int mi = 0; mi < 4; ++mi)
#pragma unroll
        for (int ni = 0; ni < 2; ++ni)
#pragma unroll
            for (int kh = 0; kh < 2; ++kh)
                acc[mi][ni] = __builtin_amdgcn_mfma_f32_16x16x32_bf16(
                    a[mi][kh], b[ni][kh], acc[mi][ni], 0, 0, 0);
    __builtin_amdgcn_s_setprio(0);

    u16* out = KVT + (size_t)bc * 4096;    // [de][dk] bf16, our dk-half
#pragma unroll
    for (int mi = 0; mi < 4; ++mi)
#pragma unroll
        for (int ni = 0; ni < 2; ++ni)
#pragma unroll
            for (int r = 0; r < 4; ++r)
                out[(mi * 16 + fq * 4 + r) * 64 + (nh * 2 + ni) * 16 + fr] =
                    f2b(acc[mi][ni][r]);
}

// ---------------- elementwise exclusive scan over chunks (bf16 in/out) ----------------
__global__ __launch_bounds__(256)
void scan_kernel(const u16* __restrict__ KVT, u16* __restrict__ STb)
{
    const int bh = blockIdx.x >> 4, sl = blockIdx.x & 15;
    const int el = sl * 256 + threadIdx.x;              // element of [de][dk]
    const u16* src = KVT + (size_t)bh * NC * 4096 + el;
    u16*      dst  = STb + (size_t)bh * NC * 4096 + el;
    float run = 0.f;
#pragma unroll 4
    for (int c = 0; c < NC; ++c) {
        dst[(size_t)c * 4096] = f2b(run);               // exclusive prefix
        run += b2f(src[(size_t)c * 4096]);
    }
}

// ======== per-chunk attention output: 2 waves/block (8 waves/CU) ========
// Wave w computes si-half {2w,2w+1} of P (disjoint P columns), then the
// ni-half {2w,2w+1} of q@ST + P@V and its output columns.
__global__ __launch_bounds__(128)
void attn_kernel(const u16* __restrict__ Qb, const u16* __restrict__ Kb,
                 const u16* __restrict__ VbT, const u16* __restrict__ STb,
                 u16* __restrict__ Ob)
{
    __shared__ u16 P[64 * 72];   // stride 72 u16 = 144B: 16B-aligned, 2-way banks
    const int blk = blockIdx.x;
    const int bh = blk >> 5, c = blk & 31;
    const int b = bh >> 4, h = bh & 15;
    const int tid = threadIdx.x, wv = tid >> 6, lane = tid & 63;
    const int fr = lane & 15, fq = lane >> 4, fk = fq * 8;
    const int tok0 = b * 2048 + c * 64;

    bf16x8 qa[4][2];
#pragma unroll
    for (int mi = 0; mi < 4; ++mi)
#pragma unroll
        for (int kh = 0; kh < 2; ++kh)
            qa[mi][kh] = *reinterpret_cast<const bf16x8*>(
                &Qb[(size_t)(tok0 + mi * 16 + fr) * 1024 + h * 64 + kh * 32 + fk]);

    // P(:, si-half) = causal-mask(q @ k^T) -> LDS bf16
    {
        bf16x8 kb[2][2];
#pragma unroll
        for (int si = 0; si < 2; ++si)
#pragma unroll
            for (int kh = 0; kh < 2; ++kh)
                kb[si][kh] = *reinterpret_cast<const bf16x8*>(
                    &Kb[(size_t)(tok0 + (wv * 2 + si) * 16 + fr) * 1024
                        + h * 64 + kh * 32 + fk]);
        f32x4 p[4][2] = {};
        __builtin_amdgcn_s_setprio(1);
#pragma unroll
        for (int mi = 0; mi < 4; ++mi)
#pragma unroll
            for (int si = 0; si < 2; ++si)
#pragma unroll
                for (int kh = 0; kh < 2; ++kh)
                    p[mi][si] = __builtin_amdgcn_mfma_f32_16x16x32_bf16(
                        qa[mi][kh], kb[si][kh], p[mi][si], 0, 0, 0);
        __builtin_amdgcn_s_setprio(0);
#pragma unroll
        for (int mi = 0; mi < 4; ++mi)
#pragma unroll
            for (int si = 0; si < 2; ++si)
#pragma unroll
                for (int r = 0; r < 4; ++r) {
                    int t = mi * 16 + fq * 4 + r;
                    int s = (wv * 2 + si) * 16 + fr;
                    float v = (s <= t) ? p[mi][si][r] : 0.0f;
                    P[t * 72 + s] = f2b(v);
                }
    }
    __syncthreads();

    f32x4 acc[4][2] = {};
    // acc = q @ ST_half   (STb[de][dk], dk-contiguous; de = ni-half)
    {
        const u16* st = STb + (size_t)blk * 4096;
        bf16x8 sb[2][2];
#pragma unroll
        for (int ni = 0; ni < 2; ++ni)
#pragma unroll
            for (int kh = 0; kh < 2; ++kh)
                sb[ni][kh] = *reinterpret_cast<const bf16x8*>(
                    &st[((wv * 2 + ni) * 16 + fr) * 64 + kh * 32 + fk]);
        __builtin_amdgcn_s_setprio(1);
#pragma unroll
        for (int mi = 0; mi < 4; ++mi)
#pragma unroll
            for (int ni = 0; ni < 2; ++ni)
#pragma unroll
                for (int kh = 0; kh < 2; ++kh)
                    acc[mi][ni] = __builtin_amdgcn_mfma_f32_16x16x32_bf16(
                        qa[mi][kh], sb[ni][kh], acc[mi][ni], 0, 0, 0);
        __builtin_amdgcn_s_setprio(0);
    }
    // acc += P @ v_half
    {
        const u16* vt = VbT + (size_t)bh * 64 * 2048;
#pragma unroll
        for (int sh = 0; sh < 2; ++sh) {
            bf16x8 pa[4], vb[2];
#pragma unroll
            for (int mi = 0; mi < 4; ++mi)
                pa[mi] = *reinterpret_cast<const bf16x8*>(
                    &P[(mi * 16 + fr) * 72 + sh * 32 + fk]);
#pragma unroll
            for (int ni = 0; ni < 2; ++ni)
                vb[ni] = *reinterpret_cast<const bf16x8*>(
                    &vt[(size_t)((wv * 2 + ni) * 16 + fr) * 2048
                        + c * 64 + sh * 32 + fk]);
            __builtin_amdgcn_s_setprio(1);
#pragma unroll
            for (int mi = 0; mi < 4; ++mi)
#pragma unroll
                for (int ni = 0; ni < 2; ++ni)
                    acc[mi][ni] = __builtin_amdgcn_mfma_f32_16x16x32_bf16(
                        pa[mi], vb[ni], acc[mi][ni], 0, 0, 0);
            __builtin_amdgcn_s_setprio(0);
        }
    }
    // write token-major bf16 O (our ni-half columns)
#pragma unroll
    for (int mi = 0; mi < 4; ++mi)
#pragma unroll
        for (int ni = 0; ni < 2; ++ni)
#pragma unroll
            for (int r = 0; r < 4; ++r) {
                int t = tok0 + mi * 16 + fq * 4 + r;
                int n = h * 64 + (wv * 2 + ni) * 16 + fr;
                Ob[(size_t)t * 1024 + n] = f2b(acc[mi][ni][r]);
            }
}

extern "C" void kernel_launch(void* const* d_in, const int* in_sizes, int n_in,
                              void* d_out, int out_size, void* d_ws, size_t ws_size,
                              hipStream_t stream)
{
    (void)in_sizes; (void)n_in; (void)out_size; (void)ws_size;
    const float* x  = (const float*)d_in[0];
    const float* Wq = (const float*)d_in[1];
    const float* bq = (const float*)d_in[2];
    const float* Wk = (const float*)d_in[3];
    const float* bk = (const float*)d_in[4];
    const float* Wv = (const float*)d_in[5];
    const float* bv = (const float*)d_in[6];
    const float* Wo = (const float*)d_in[7];
    const float* bo = (const float*)d_in[8];
    float* out = (float*)d_out;

    char* ws = (char*)d_ws;
    constexpr size_t SZ_ME = (size_t)Mq * Eq * 2;        // 8 MB
    u16*   Qb  = (u16*)  (ws + 0 * SZ_ME);
    u16*   Kb  = (u16*)  (ws + 1 * SZ_ME);
    u16*   KbT = (u16*)  (ws + 2 * SZ_ME);
    u16*   VbT = (u16*)  (ws + 3 * SZ_ME);
    u16*   Ob  = (u16*)  (ws + 4 * SZ_ME);
    u16*   KVT = (u16*)  (ws + 5 * SZ_ME);               // 8 MB bf16
    u16*   STb = (u16*)  (ws + 6 * SZ_ME);
    u16*   Xb  = (u16*)  (ws + 7 * SZ_ME);
    u16*   Wb0 = (u16*)  (ws + 8 * SZ_ME);               // [Wq|Wk|Wv|Wo] bf16
    u16* Wqkvb = Wb0;
    u16* Wob   = Wb0 + (size_t)3 * Eq * Eq;

    // 1) all bf16 conversions, one launch
    cvt_all_kernel<<<dim3(8192), dim3(256), 0, stream>>>(x, Wq, Wk, Wv, Wo, Xb, Wb0);

    // 2) fused QKV projection (M=4096, N=3072): ring GEMM, 768 blocks x 512 thr
    qkv_ring<<<dim3(768), dim3(512), 0, stream>>>(
        Xb, Wqkvb, bq, bk, bv, Qb, Kb, KbT, VbT);

    // 3) attention: ni-split chunk_kv (2048 blk), scan, 2-wave attn (1024 blk)
    chunk_kv_kernel<<<dim3(BH * NC * 2), dim3(64), 0, stream>>>(KbT, VbT, KVT);
    scan_kernel<<<dim3(BH * 16), dim3(256), 0, stream>>>(KVT, STb);
    attn_kernel<<<dim3(BH * NC), dim3(128), 0, stream>>>(Qb, Kb, VbT, STb, Ob);

    // 4) output projection (M=4096, N=1024): ring GEMM, 512 blocks (2/CU)
    oproj_kernel<<<dim3(512), dim3(256), 0, stream>>>(Ob, Wob, bo, out);
}

// Round 15
// 89.394 us; speedup vs baseline: 1.3864x; 1.0054x over previous
//
#include <hip/hip_runtime.h>
#include <hip/hip_bf16.h>
#include <cmath>

typedef unsigned short u16;
typedef __bf16 bf16x8 __attribute__((ext_vector_type(8)));
typedef float  f32x4  __attribute__((ext_vector_type(4)));
typedef float  f4     __attribute__((ext_vector_type(4)));
typedef u16    us4    __attribute__((ext_vector_type(4)));

#define DEVFN __device__ __forceinline__

static constexpr int Bq = 2, Nq = 2048, Eq = 1024;
static constexpr int Mq = Bq * Nq;        // 4096 tokens
static constexpr int CHK = 64;            // attention chunk
static constexpr int NC  = Nq / CHK;      // 32 chunks
static constexpr int BH  = Bq * 16;       // 32

DEVFN u16 f2b(float f) {                  // f32 -> bf16 (RNE), finite inputs
    union { float f; unsigned int u; } x; x.f = f;
    unsigned int r = x.u + 0x7fffu + ((x.u >> 16) & 1u);
    return (u16)(r >> 16);
}
DEVFN float b2f(u16 v) {
    union { unsigned int u; float f; } x; x.u = ((unsigned int)v) << 16; return x.f;
}

DEVFN void gl_lds16(const u16* g, u16* l) {  // async 16B global->LDS (dest: wave base + lane*16)
    __builtin_amdgcn_global_load_lds(
        (const __attribute__((address_space(1))) unsigned int*)(g),
        (__attribute__((address_space(3))) unsigned int*)(l),
        16, 0, 0);
}

// ---------------- all f32 -> bf16 converts in ONE launch ----------------
__global__ __launch_bounds__(256)
void cvt_all_kernel(const float* __restrict__ x,
                    const float* __restrict__ w0, const float* __restrict__ w1,
                    const float* __restrict__ w2, const float* __restrict__ w3,
                    u16* __restrict__ Xb, u16* __restrict__ Wb)
{
    const int blk = blockIdx.x;
    const float* s; u16* d; int i;
    if (blk < 4096) {
        i = blk * 256 + threadIdx.x;  s = x;  d = Xb;
    } else {
        const int wsel = (blk - 4096) >> 10;
        i = ((blk - 4096) & 1023) * 256 + threadIdx.x;
        s = (wsel == 0) ? w0 : (wsel == 1) ? w1 : (wsel == 2) ? w2 : w3;
        d = Wb + (size_t)wsel * (Eq * Eq);
    }
    f4 v = *reinterpret_cast<const f4*>(&s[(size_t)i * 4]);
    us4 p; p[0] = f2b(v[0]); p[1] = f2b(v[1]); p[2] = f2b(v[2]); p[3] = f2b(v[3]);
    *reinterpret_cast<us4*>(&d[(size_t)i * 4]) = p;
}

// ======== QKV ring GEMM: 128x128 tile, 8 waves (32x64 each), BK=32, ring-2 ========
// R10 tiling at MAX occupancy: 2 buffers x 16KB = 32KB -> 4 blocks/CU = 32 waves/CU.
// Per iter t: stage t+1 into buf[(t+1)&1] (free since iter t-1's barrier);
// ds_read+MFMA buf[t&1]; vmcnt(0) drain; s_barrier. TLP hides the drain.
// Swizzle sigma(row)=(row>>1)&3 both sides (R6-proven 0 conflicts).
__global__ __launch_bounds__(512, 8)
void qkv_ring(const u16* __restrict__ X, const u16* __restrict__ W,
              const float* __restrict__ b0, const float* __restrict__ b1,
              const float* __restrict__ b2,
              u16* __restrict__ Qb, u16* __restrict__ Kb, u16* __restrict__ KbT,
              u16* __restrict__ VbT)
{
    constexpr int BUFU = 8192;                // 16KB: A 4096 u16 | B 4096 u16
    __shared__ u16 lds[2 * BUFU];             // 32KB -> 4 blocks/CU (wave-capped)
    const int tid = threadIdx.x, wid = tid >> 6, lane = tid & 63;
    const int wr = (wid >> 1) * 32, wc = (wid & 1) * 64;   // wave: 32 rows x 64 cols
    const int fr = lane & 15, fq = lane >> 4;

    const int bid = blockIdx.x;               // grid 768 = 8 * 96 (XCD-bijective)
    const int fid = (bid & 7) * 96 + (bid >> 3);
    const int bx = fid % 24, by = fid / 24;
    const int m0 = by * 128, n0 = bx * 128;

    // staging: one round = 512 thr x 16B = 128 rows x 4 slots (full matrix)
    const int row0 = tid >> 2;
    const int sc   = ((tid & 3) ^ ((row0 >> 1) & 3)) * 8;   // swizzled source slot
    const u16* gA = X + (size_t)(m0 + row0) * 1024 + sc;
    const u16* gB = W + (size_t)(n0 + row0) * 1024 + sc;
    const int dw = wid * 512;                 // wave-uniform dest piece (1KB/wave)

    // fragment reads: same involution on read side
    const int fsw = (fq ^ ((fr >> 1) & 3)) << 3;
    int aoff[2], boff[4];
#pragma unroll
    for (int mi = 0; mi < 2; ++mi) aoff[mi] = (wr + mi * 16 + fr) * 32 + fsw;
#pragma unroll
    for (int ni = 0; ni < 4; ++ni) boff[ni] = 4096 + (wc + ni * 16 + fr) * 32 + fsw;

#define STAGE(kt, bs) do { u16* _b = lds + (bs) * BUFU;                        \
        gl_lds16(gA + (kt) * 32, _b + dw);                                     \
        gl_lds16(gB + (kt) * 32, _b + 4096 + dw); } while (0)

    // prologue: tile0 staged and drained
    STAGE(0, 0);
    asm volatile("s_waitcnt vmcnt(0)" ::: "memory");
    __builtin_amdgcn_sched_barrier(0);
    __builtin_amdgcn_s_barrier();

    f32x4 acc[2][4] = {};

    for (int t = 0; t < 32; ++t) {
        if (t + 1 < 32) STAGE(t + 1, (t + 1) & 1);   // buffer free since iter t-1's barrier
        const u16* buf = lds + (t & 1) * BUFU;
        bf16x8 af[2], bfv[4];
#pragma unroll
        for (int mi = 0; mi < 2; ++mi)
            af[mi] = *reinterpret_cast<const bf16x8*>(&buf[aoff[mi]]);
#pragma unroll
        for (int ni = 0; ni < 4; ++ni)
            bfv[ni] = *reinterpret_cast<const bf16x8*>(&buf[boff[ni]]);
        __builtin_amdgcn_s_setprio(1);
#pragma unroll
        for (int mi = 0; mi < 2; ++mi)
#pragma unroll
            for (int ni = 0; ni < 4; ++ni)
                acc[mi][ni] = __builtin_amdgcn_mfma_f32_16x16x32_bf16(
                    af[mi], bfv[ni], acc[mi][ni], 0, 0, 0);
        __builtin_amdgcn_s_setprio(0);
        // tile t+1 must have landed before next iter reads it
        asm volatile("s_waitcnt vmcnt(0)" ::: "memory");
        __builtin_amdgcn_sched_barrier(0);
        __builtin_amdgcn_s_barrier();
    }
#undef STAGE

    const int nw  = n0 + wc;                           // 64-aligned, seg-uniform
    const int seg = nw >> 10;                          // 0=q 1=k 2=v
    const float* bp = (seg == 0) ? b0 : (seg == 1) ? b1 : b2;
#pragma unroll
    for (int mi = 0; mi < 2; ++mi)
#pragma unroll
        for (int ni = 0; ni < 4; ++ni) {
            const int nl    = (nw & 1023) + ni * 16 + fr;
            const int mbase = m0 + wr + mi * 16 + fq * 4;
            const float bn  = bp[nl];
            float vr[4];
#pragma unroll
            for (int r = 0; r < 4; ++r) {
                float v = acc[mi][ni][r] + bn;
                if (seg < 2) v = (v > 0.f) ? (v + 1.f) : __expf(v);  // elu+1
                vr[r] = v;
            }
            if (seg == 0) {
#pragma unroll
                for (int r = 0; r < 4; ++r)
                    Qb[(size_t)(mbase + r) * 1024 + nl] = f2b(vr[r]);
            } else {
                us4 pk;
#pragma unroll
                for (int r = 0; r < 4; ++r) pk[r] = f2b(vr[r]);
                const int bb = mbase >> 11, nt = mbase & 2047;
                const int hh = nl >> 6,     dd = nl & 63;
                u16* T = (seg == 1) ? KbT : VbT;
                *reinterpret_cast<us4*>(
                    &T[((size_t)(bb * 16 + hh) * 64 + dd) * 2048 + nt]) = pk;
                if (seg == 1) {
#pragma unroll
                    for (int r = 0; r < 4; ++r)
                        Kb[(size_t)(mbase + r) * 1024 + nl] = f2b(vr[r]);
                }
            }
        }
}

// ======== O-proj: 64x128 tile, 4 waves, BK=32, ring-3, dup-free (verified) ========
__global__ __launch_bounds__(256)
void oproj_kernel(const u16* __restrict__ X, const u16* __restrict__ W,
                  const float* __restrict__ b0, float* __restrict__ outF)
{
    constexpr int BUFU = (64 + 128) * 32;     // 6144 u16 = 12KB per buffer
    __shared__ u16 lds[3 * BUFU];             // 36KB
    const int tid = threadIdx.x, wid = tid >> 6, lane = tid & 63;
    const int wr = (wid >> 1) * 32, wc = (wid & 1) * 64;
    const int fr = lane & 15, fq = lane >> 4;

    const int bid = blockIdx.x;               // grid 512 = 8 * 64
    const int fid = (bid & 7) * 64 + (bid >> 3);
    const int bx = fid & 7, by = fid >> 3;
    const int m0 = by * 64, n0 = bx * 128;

    const int ra = tid >> 2;
    const int sc = ((tid & 3) ^ ((tid >> 3) & 3)) * 8;
    const u16* gA = X + (size_t)(m0 + ra) * 1024 + sc;
    const u16* gB = W + (size_t)(n0 + ra) * 1024 + sc;
    const int dw = wid * 512;

    const int fsw = (fq ^ ((fr >> 1) & 3)) << 3;
    int aoff[2], boff[4];
#pragma unroll
    for (int mi = 0; mi < 2; ++mi) aoff[mi] = (wr + mi * 16 + fr) * 32 + fsw;
#pragma unroll
    for (int ni = 0; ni < 4; ++ni) boff[ni] = 2048 + (wc + ni * 16 + fr) * 32 + fsw;

#define STAGE(kt, bs) do { u16* _b = lds + (bs) * BUFU;                          \
        gl_lds16(gA + (kt) * 32,             _b + dw);                           \
        gl_lds16(gB + (kt) * 32,             _b + 2048 + dw);                    \
        gl_lds16(gB + (kt) * 32 + 64 * 1024, _b + 4096 + dw); } while (0)

    STAGE(0, 0);
    STAGE(1, 1);
    asm volatile("s_waitcnt vmcnt(3)" ::: "memory");
    __builtin_amdgcn_sched_barrier(0);
    __builtin_amdgcn_s_barrier();

    f32x4 acc[2][4] = {};
    int cb = 0, sb = 2;

    for (int t = 0; t < 32; ++t) {
        if (t + 2 < 32) STAGE(t + 2, sb);
        const u16* buf = lds + cb * BUFU;
        bf16x8 af[2], bfv[4];
#pragma unroll
        for (int mi = 0; mi < 2; ++mi)
            af[mi] = *reinterpret_cast<const bf16x8*>(&buf[aoff[mi]]);
#pragma unroll
        for (int ni = 0; ni < 4; ++ni)
            bfv[ni] = *reinterpret_cast<const bf16x8*>(&buf[boff[ni]]);
        __builtin_amdgcn_s_setprio(1);
#pragma unroll
        for (int mi = 0; mi < 2; ++mi)
#pragma unroll
            for (int ni = 0; ni < 4; ++ni)
                acc[mi][ni] = __builtin_amdgcn_mfma_f32_16x16x32_bf16(
                    af[mi], bfv[ni], acc[mi][ni], 0, 0, 0);
        __builtin_amdgcn_s_setprio(0);
        if (t < 30)       asm volatile("s_waitcnt vmcnt(3)" ::: "memory");
        else if (t == 30) asm volatile("s_waitcnt vmcnt(0)" ::: "memory");
        __builtin_amdgcn_sched_barrier(0);
        __builtin_amdgcn_s_barrier();
        cb = (cb == 2) ? 0 : cb + 1;
        sb = (sb == 2) ? 0 : sb + 1;
    }
#undef STAGE

#pragma unroll
    for (int mi = 0; mi < 2; ++mi)
#pragma unroll
        for (int ni = 0; ni < 4; ++ni) {
            const int n     = n0 + wc + ni * 16 + fr;
            const int mbase = m0 + wr + mi * 16 + fq * 4;
            const float bn  = b0[n];
#pragma unroll
            for (int r = 0; r < 4; ++r)
                outF[(size_t)(mbase + r) * 1024 + n] = acc[mi][ni][r] + bn;
        }
}

// ======== per-chunk KV^T = v^T @ k, ni-split: 2048 one-wave blocks (8 waves/CU) ========
__global__ __launch_bounds__(64)
void chunk_kv_kernel(const u16* __restrict__ KbT, const u16* __restrict__ VbT,
                     u16* __restrict__ KVT)
{
    const int blk = blockIdx.x;          // (bh*NC + c)*2 + nh
    const int nh = blk & 1;
    const int bc = blk >> 1;
    const int bh = bc >> 5, c = bc & 31;
    const int lane = threadIdx.x;
    const int fr = lane & 15, fq = lane >> 4, fk = fq * 8;
    const u16* kt = KbT + (size_t)bh * 64 * 2048;
    const u16* vt = VbT + (size_t)bh * 64 * 2048;

    bf16x8 a[4][2], b[2][2];             // a = V rows (de, all), b = K rows (ni-half)
#pragma unroll
    for (int mi = 0; mi < 4; ++mi)
#pragma unroll
        for (int kh = 0; kh < 2; ++kh)
            a[mi][kh] = *reinterpret_cast<const bf16x8*>(
                &vt[(size_t)(mi * 16 + fr) * 2048 + c * 64 + kh * 32 + fk]);
#pragma unroll
    for (int ni = 0; ni < 2; ++ni)
#pragma unroll
        for (int kh = 0; kh < 2; ++kh)
            b[ni][kh] = *reinterpret_cast<const bf16x8*>(
                &kt[(size_t)((nh * 2 + ni) * 16 + fr) * 2048 + c * 64 + kh * 32 + fk]);

    f32x4 acc[4][2] = {};
    __builtin_amdgcn_s_setprio(1);
#pragma unroll
    for (int mi = 0; mi < 4; ++mi)
#pragma unroll
        for (int ni = 0; ni < 2; ++ni)
#pragma unroll
            for (int kh = 0; kh < 2; ++kh)
                acc[mi][ni] = __builtin_amdgcn_mfma_f32_16x16x32_bf16(
                    a[mi][kh], b[ni][kh], acc[mi][ni], 0, 0, 0);
    __builtin_amdgcn_s_setprio(0);

    u16* out = KVT + (size_t)bc * 4096;    // [de][dk] bf16, our dk-half
#pragma unroll
    for (int mi = 0; mi < 4; ++mi)
#pragma unroll
        for (int ni = 0; ni < 2; ++ni)
#pragma unroll
            for (int r = 0; r < 4; ++r)
                out[(mi * 16 + fq * 4 + r) * 64 + (nh * 2 + ni) * 16 + fr] =
                    f2b(acc[mi][ni][r]);
}

// ---------------- elementwise exclusive scan over chunks (bf16 in/out) ----------------
__global__ __launch_bounds__(256)
void scan_kernel(const u16* __restrict__ KVT, u16* __restrict__ STb)
{
    const int bh = blockIdx.x >> 4, sl = blockIdx.x & 15;
    const int el = sl * 256 + threadIdx.x;              // element of [de][dk]
    const u16* src = KVT + (size_t)bh * NC * 4096 + el;
    u16*      dst  = STb + (size_t)bh * NC * 4096 + el;
    float run = 0.f;
#pragma unroll 4
    for (int c = 0; c < NC; ++c) {
        dst[(size_t)c * 4096] = f2b(run);               // exclusive prefix
        run += b2f(src[(size_t)c * 4096]);
    }
}

// ======== per-chunk attention output: 2 waves/block (8 waves/CU) ========
__global__ __launch_bounds__(128)
void attn_kernel(const u16* __restrict__ Qb, const u16* __restrict__ Kb,
                 const u16* __restrict__ VbT, const u16* __restrict__ STb,
                 u16* __restrict__ Ob)
{
    __shared__ u16 P[64 * 72];   // stride 72 u16 = 144B: 16B-aligned, 2-way banks
    const int blk = blockIdx.x;
    const int bh = blk >> 5, c = blk & 31;
    const int b = bh >> 4, h = bh & 15;
    const int tid = threadIdx.x, wv = tid >> 6, lane = tid & 63;
    const int fr = lane & 15, fq = lane >> 4, fk = fq * 8;
    const int tok0 = b * 2048 + c * 64;

    bf16x8 qa[4][2];
#pragma unroll
    for (int mi = 0; mi < 4; ++mi)
#pragma unroll
        for (int kh = 0; kh < 2; ++kh)
            qa[mi][kh] = *reinterpret_cast<const bf16x8*>(
                &Qb[(size_t)(tok0 + mi * 16 + fr) * 1024 + h * 64 + kh * 32 + fk]);

    // P(:, si-half) = causal-mask(q @ k^T) -> LDS bf16
    {
        bf16x8 kb[2][2];
#pragma unroll
        for (int si = 0; si < 2; ++si)
#pragma unroll
            for (int kh = 0; kh < 2; ++kh)
                kb[si][kh] = *reinterpret_cast<const bf16x8*>(
                    &Kb[(size_t)(tok0 + (wv * 2 + si) * 16 + fr) * 1024
                        + h * 64 + kh * 32 + fk]);
        f32x4 p[4][2] = {};
        __builtin_amdgcn_s_setprio(1);
#pragma unroll
        for (int mi = 0; mi < 4; ++mi)
#pragma unroll
            for (int si = 0; si < 2; ++si)
#pragma unroll
                for (int kh = 0; kh < 2; ++kh)
                    p[mi][si] = __builtin_amdgcn_mfma_f32_16x16x32_bf16(
                        qa[mi][kh], kb[si][kh], p[mi][si], 0, 0, 0);
        __builtin_amdgcn_s_setprio(0);
#pragma unroll
        for (int mi = 0; mi < 4; ++mi)
#pragma unroll
            for (int si = 0; si < 2; ++si)
#pragma unroll
                for (int r = 0; r < 4; ++r) {
                    int t = mi * 16 + fq * 4 + r;
                    int s = (wv * 2 + si) * 16 + fr;
                    float v = (s <= t) ? p[mi][si][r] : 0.0f;
                    P[t * 72 + s] = f2b(v);
                }
    }
    __syncthreads();

    f32x4 acc[4][2] = {};
    // acc = q @ ST_half   (STb[de][dk], dk-contiguous; de = ni-half)
    {
        const u16* st = STb + (size_t)blk * 4096;
        bf16x8 sb[2][2];
#pragma unroll
        for (int ni = 0; ni < 2; ++ni)
#pragma unroll
            for (int kh = 0; kh < 2; ++kh)
                sb[ni][kh] = *reinterpret_cast<const bf16x8*>(
                    &st[((wv * 2 + ni) * 16 + fr) * 64 + kh * 32 + fk]);
        __builtin_amdgcn_s_setprio(1);
#pragma unroll
        for (int mi = 0; mi < 4; ++mi)
#pragma unroll
            for (int ni = 0; ni < 2; ++ni)
#pragma unroll
                for (int kh = 0; kh < 2; ++kh)
                    acc[mi][ni] = __builtin_amdgcn_mfma_f32_16x16x32_bf16(
                        qa[mi][kh], sb[ni][kh], acc[mi][ni], 0, 0, 0);
        __builtin_amdgcn_s_setprio(0);
    }
    // acc += P @ v_half
    {
        const u16* vt = VbT + (size_t)bh * 64 * 2048;
#pragma unroll
        for (int sh = 0; sh < 2; ++sh) {
            bf16x8 pa[4], vb[2];
#pragma unroll
            for (int mi = 0; mi < 4; ++mi)
                pa[mi] = *reinterpret_cast<const bf16x8*>(
                    &P[(mi * 16 + fr) * 72 + sh * 32 + fk]);
#pragma unroll
            for (int ni = 0; ni < 2; ++ni)
                vb[ni] = *reinterpret_cast<const bf16x8*>(
                    &vt[(size_t)((wv * 2 + ni) * 16 + fr) * 2048
                        + c * 64 + sh * 32 + fk]);
            __builtin_amdgcn_s_setprio(1);
#pragma unroll
            for (int mi = 0; mi < 4; ++mi)
#pragma unroll
                for (int ni = 0; ni < 2; ++ni)
                    acc[mi][ni] = __builtin_amdgcn_mfma_f32_16x16x32_bf16(
                        pa[mi], vb[ni], acc[mi][ni], 0, 0, 0);
            __builtin_amdgcn_s_setprio(0);
        }
    }
    // write token-major bf16 O (our ni-half columns)
#pragma unroll
    for (int mi = 0; mi < 4; ++mi)
#pragma unroll
        for (int ni = 0; ni < 2; ++ni)
#pragma unroll
            for (int r = 0; r < 4; ++r) {
                int t = tok0 + mi * 16 + fq * 4 + r;
                int n = h * 64 + (wv * 2 + ni) * 16 + fr;
                Ob[(size_t)t * 1024 + n] = f2b(acc[mi][ni][r]);
            }
}

extern "C" void kernel_launch(void* const* d_in, const int* in_sizes, int n_in,
                              void* d_out, int out_size, void* d_ws, size_t ws_size,
                              hipStream_t stream)
{
    (void)in_sizes; (void)n_in; (void)out_size; (void)ws_size;
    const float* x  = (const float*)d_in[0];
    const float* Wq = (const float*)d_in[1];
    const float* bq = (const float*)d_in[2];
    const float* Wk = (const float*)d_in[3];
    const float* bk = (const float*)d_in[4];
    const float* Wv = (const float*)d_in[5];
    const float* bv = (const float*)d_in[6];
    const float* Wo = (const float*)d_in[7];
    const float* bo = (const float*)d_in[8];
    float* out = (float*)d_out;

    char* ws = (char*)d_ws;
    constexpr size_t SZ_ME = (size_t)Mq * Eq * 2;        // 8 MB
    u16*   Qb  = (u16*)  (ws + 0 * SZ_ME);
    u16*   Kb  = (u16*)  (ws + 1 * SZ_ME);
    u16*   KbT = (u16*)  (ws + 2 * SZ_ME);
    u16*   VbT = (u16*)  (ws + 3 * SZ_ME);
    u16*   Ob  = (u16*)  (ws + 4 * SZ_ME);
    u16*   KVT = (u16*)  (ws + 5 * SZ_ME);               // 8 MB bf16
    u16*   STb = (u16*)  (ws + 6 * SZ_ME);
    u16*   Xb  = (u16*)  (ws + 7 * SZ_ME);
    u16*   Wb0 = (u16*)  (ws + 8 * SZ_ME);               // [Wq|Wk|Wv|Wo] bf16
    u16* Wqkvb = Wb0;
    u16* Wob   = Wb0 + (size_t)3 * Eq * Eq;

    // 1) all bf16 conversions, one launch
    cvt_all_kernel<<<dim3(8192), dim3(256), 0, stream>>>(x, Wq, Wk, Wv, Wo, Xb, Wb0);

    // 2) fused QKV projection (M=4096, N=3072): ring-2 GEMM, 768 blocks x 512 thr
    qkv_ring<<<dim3(768), dim3(512), 0, stream>>>(
        Xb, Wqkvb, bq, bk, bv, Qb, Kb, KbT, VbT);

    // 3) attention: ni-split chunk_kv (2048 blk), scan, 2-wave attn (1024 blk)
    chunk_kv_kernel<<<dim3(BH * NC * 2), dim3(64), 0, stream>>>(KbT, VbT, KVT);
    scan_kernel<<<dim3(BH * 16), dim3(256), 0, stream>>>(KVT, STb);
    attn_kernel<<<dim3(BH * NC), dim3(128), 0, stream>>>(Qb, Kb, VbT, STb, Ob);

    // 4) output projection (M=4096, N=1024): ring GEMM, 512 blocks (2/CU)
    oproj_kernel<<<dim3(512), dim3(256), 0, stream>>>(Ob, Wob, bo, out);
}

// Round 16
// 89.281 us; speedup vs baseline: 1.3881x; 1.0013x over previous
//
#include <hip/hip_runtime.h>
#include <hip/hip_bf16.h>
#include <cmath>

typedef unsigned short u16;
typedef __bf16 bf16x8 __attribute__((ext_vector_type(8)));
typedef float  f32x4  __attribute__((ext_vector_type(4)));
typedef float  f4     __attribute__((ext_vector_type(4)));
typedef u16    us4    __attribute__((ext_vector_type(4)));

#define DEVFN __device__ __forceinline__

static constexpr int Bq = 2, Nq = 2048, Eq = 1024;
static constexpr int Mq = Bq * Nq;        // 4096 tokens
static constexpr int CHK = 64;            // attention chunk
static constexpr int NC  = Nq / CHK;      // 32 chunks
static constexpr int BH  = Bq * 16;       // 32

DEVFN u16 f2b(float f) {                  // f32 -> bf16 (RNE), finite inputs
    union { float f; unsigned int u; } x; x.f = f;
    unsigned int r = x.u + 0x7fffu + ((x.u >> 16) & 1u);
    return (u16)(r >> 16);
}
DEVFN float b2f(u16 v) {
    union { unsigned int u; float f; } x; x.u = ((unsigned int)v) << 16; return x.f;
}

DEVFN void gl_lds16(const u16* g, u16* l) {  // async 16B global->LDS (dest: wave base + lane*16)
    __builtin_amdgcn_global_load_lds(
        (const __attribute__((address_space(1))) unsigned int*)(g),
        (__attribute__((address_space(3))) unsigned int*)(l),
        16, 0, 0);
}

// ---------------- all f32 -> bf16 converts in ONE launch ----------------
__global__ __launch_bounds__(256)
void cvt_all_kernel(const float* __restrict__ x,
                    const float* __restrict__ w0, const float* __restrict__ w1,
                    const float* __restrict__ w2, const float* __restrict__ w3,
                    u16* __restrict__ Xb, u16* __restrict__ Wb)
{
    const int blk = blockIdx.x;
    const float* s; u16* d; int i;
    if (blk < 4096) {
        i = blk * 256 + threadIdx.x;  s = x;  d = Xb;
    } else {
        const int wsel = (blk - 4096) >> 10;
        i = ((blk - 4096) & 1023) * 256 + threadIdx.x;
        s = (wsel == 0) ? w0 : (wsel == 1) ? w1 : (wsel == 2) ? w2 : w3;
        d = Wb + (size_t)wsel * (Eq * Eq);
    }
    f4 v = *reinterpret_cast<const f4*>(&s[(size_t)i * 4]);
    us4 p; p[0] = f2b(v[0]); p[1] = f2b(v[1]); p[2] = f2b(v[2]); p[3] = f2b(v[3]);
    *reinterpret_cast<us4*>(&d[(size_t)i * 4]) = p;
}

// ======== QKV ring GEMM: 128x128 tile, 8 waves (32x64), BK=64, ring-2 ========
// Cadence experiment: 16 K-steps (was 32) — one drain+barrier per 64 K-columns.
// LDS 2 x 32KB = 64KB -> 2 blocks/CU (16 waves/CU). Per iter: 2 kk-substeps of
// {6 ds_read_b128 + 8 MFMA}. Swizzle sigma(row)=row&7 over 8 slots of the 128B
// row, same involution both sides (2 lanes/bank = free, m136).
__global__ __launch_bounds__(512, 4)
void qkv_ring(const u16* __restrict__ X, const u16* __restrict__ W,
              const float* __restrict__ b0, const float* __restrict__ b1,
              const float* __restrict__ b2,
              u16* __restrict__ Qb, u16* __restrict__ Kb, u16* __restrict__ KbT,
              u16* __restrict__ VbT)
{
    constexpr int BUFU = 16384;               // 32KB: A 8192 u16 | B 8192 u16
    __shared__ u16 lds[2 * BUFU];             // 64KB -> 2 blocks/CU
    const int tid = threadIdx.x, wid = tid >> 6, lane = tid & 63;
    const int wr = (wid >> 1) * 32, wc = (wid & 1) * 64;   // wave: 32 rows x 64 cols
    const int fr = lane & 15, fq = lane >> 4;

    const int bid = blockIdx.x;               // grid 768 = 8 * 96 (XCD-bijective)
    const int fid = (bid & 7) * 96 + (bid >> 3);
    const int bx = fid % 24, by = fid / 24;
    const int m0 = by * 128, n0 = bx * 128;

    // staging: one round = 512 thr x 16B = 64 rows x 8 slots; 2 rounds per matrix
    const int row0 = tid >> 3;                               // 0..63
    const int sc   = ((tid & 7) ^ (row0 & 7)) * 8;           // swizzled source slot
    const u16* gA = X + (size_t)(m0 + row0) * 1024 + sc;
    const u16* gB = W + (size_t)(n0 + row0) * 1024 + sc;
    const int dw = wid * 512;                 // wave-uniform piece within each round

    // fragment reads: same involution; rows' &7 == fr&7 (bases are mult of 16)
    int aoff[2][2], boff[2][4];
#pragma unroll
    for (int kk = 0; kk < 2; ++kk) {
        const int slot = ((kk * 4 + fq) ^ (fr & 7)) << 3;
#pragma unroll
        for (int mi = 0; mi < 2; ++mi)
            aoff[kk][mi] = (wr + mi * 16 + fr) * 64 + slot;
#pragma unroll
        for (int ni = 0; ni < 4; ++ni)
            boff[kk][ni] = 8192 + (wc + ni * 16 + fr) * 64 + slot;
    }

#define STAGE(kt, bs) do { u16* _b = lds + (bs) * BUFU;                        \
        gl_lds16(gA + (kt) * 64,              _b + dw);                        \
        gl_lds16(gA + (kt) * 64 + 64 * 1024,  _b + 4096 + dw);                 \
        gl_lds16(gB + (kt) * 64,              _b + 8192 + dw);                 \
        gl_lds16(gB + (kt) * 64 + 64 * 1024,  _b + 12288 + dw); } while (0)

    // prologue: tile0 staged and drained
    STAGE(0, 0);
    asm volatile("s_waitcnt vmcnt(0)" ::: "memory");
    __builtin_amdgcn_sched_barrier(0);
    __builtin_amdgcn_s_barrier();

    f32x4 acc[2][4] = {};

    for (int t = 0; t < 16; ++t) {
        if (t + 1 < 16) STAGE(t + 1, (t + 1) & 1);   // buffer free since iter t-1's barrier
        const u16* buf = lds + (t & 1) * BUFU;
#pragma unroll
        for (int kk = 0; kk < 2; ++kk) {
            bf16x8 af[2], bfv[4];
#pragma unroll
            for (int mi = 0; mi < 2; ++mi)
                af[mi] = *reinterpret_cast<const bf16x8*>(&buf[aoff[kk][mi]]);
#pragma unroll
            for (int ni = 0; ni < 4; ++ni)
                bfv[ni] = *reinterpret_cast<const bf16x8*>(&buf[boff[kk][ni]]);
            __builtin_amdgcn_s_setprio(1);
#pragma unroll
            for (int mi = 0; mi < 2; ++mi)
#pragma unroll
                for (int ni = 0; ni < 4; ++ni)
                    acc[mi][ni] = __builtin_amdgcn_mfma_f32_16x16x32_bf16(
                        af[mi], bfv[ni], acc[mi][ni], 0, 0, 0);
            __builtin_amdgcn_s_setprio(0);
        }
        // tile t+1 must have landed before next iter reads it
        asm volatile("s_waitcnt vmcnt(0)" ::: "memory");
        __builtin_amdgcn_sched_barrier(0);
        __builtin_amdgcn_s_barrier();
    }
#undef STAGE

    const int nw  = n0 + wc;                           // 64-aligned, seg-uniform
    const int seg = nw >> 10;                          // 0=q 1=k 2=v
    const float* bp = (seg == 0) ? b0 : (seg == 1) ? b1 : b2;
#pragma unroll
    for (int mi = 0; mi < 2; ++mi)
#pragma unroll
        for (int ni = 0; ni < 4; ++ni) {
            const int nl    = (nw & 1023) + ni * 16 + fr;
            const int mbase = m0 + wr + mi * 16 + fq * 4;
            const float bn  = bp[nl];
            float vr[4];
#pragma unroll
            for (int r = 0; r < 4; ++r) {
                float v = acc[mi][ni][r] + bn;
                if (seg < 2) v = (v > 0.f) ? (v + 1.f) : __expf(v);  // elu+1
                vr[r] = v;
            }
            if (seg == 0) {
#pragma unroll
                for (int r = 0; r < 4; ++r)
                    Qb[(size_t)(mbase + r) * 1024 + nl] = f2b(vr[r]);
            } else {
                us4 pk;
#pragma unroll
                for (int r = 0; r < 4; ++r) pk[r] = f2b(vr[r]);
                const int bb = mbase >> 11, nt = mbase & 2047;
                const int hh = nl >> 6,     dd = nl & 63;
                u16* T = (seg == 1) ? KbT : VbT;
                *reinterpret_cast<us4*>(
                    &T[((size_t)(bb * 16 + hh) * 64 + dd) * 2048 + nt]) = pk;
                if (seg == 1) {
#pragma unroll
                    for (int r = 0; r < 4; ++r)
                        Kb[(size_t)(mbase + r) * 1024 + nl] = f2b(vr[r]);
                }
            }
        }
}

// ======== O-proj: 64x128 tile, 4 waves, BK=32, ring-3, dup-free (verified) ========
__global__ __launch_bounds__(256)
void oproj_kernel(const u16* __restrict__ X, const u16* __restrict__ W,
                  const float* __restrict__ b0, float* __restrict__ outF)
{
    constexpr int BUFU = (64 + 128) * 32;     // 6144 u16 = 12KB per buffer
    __shared__ u16 lds[3 * BUFU];             // 36KB
    const int tid = threadIdx.x, wid = tid >> 6, lane = tid & 63;
    const int wr = (wid >> 1) * 32, wc = (wid & 1) * 64;
    const int fr = lane & 15, fq = lane >> 4;

    const int bid = blockIdx.x;               // grid 512 = 8 * 64
    const int fid = (bid & 7) * 64 + (bid >> 3);
    const int bx = fid & 7, by = fid >> 3;
    const int m0 = by * 64, n0 = bx * 128;

    const int ra = tid >> 2;
    const int sc = ((tid & 3) ^ ((tid >> 3) & 3)) * 8;
    const u16* gA = X + (size_t)(m0 + ra) * 1024 + sc;
    const u16* gB = W + (size_t)(n0 + ra) * 1024 + sc;
    const int dw = wid * 512;

    const int fsw = (fq ^ ((fr >> 1) & 3)) << 3;
    int aoff[2], boff[4];
#pragma unroll
    for (int mi = 0; mi < 2; ++mi) aoff[mi] = (wr + mi * 16 + fr) * 32 + fsw;
#pragma unroll
    for (int ni = 0; ni < 4; ++ni) boff[ni] = 2048 + (wc + ni * 16 + fr) * 32 + fsw;

#define STAGE(kt, bs) do { u16* _b = lds + (bs) * BUFU;                          \
        gl_lds16(gA + (kt) * 32,             _b + dw);                           \
        gl_lds16(gB + (kt) * 32,             _b + 2048 + dw);                    \
        gl_lds16(gB + (kt) * 32 + 64 * 1024, _b + 4096 + dw); } while (0)

    STAGE(0, 0);
    STAGE(1, 1);
    asm volatile("s_waitcnt vmcnt(3)" ::: "memory");
    __builtin_amdgcn_sched_barrier(0);
    __builtin_amdgcn_s_barrier();

    f32x4 acc[2][4] = {};
    int cb = 0, sb = 2;

    for (int t = 0; t < 32; ++t) {
        if (t + 2 < 32) STAGE(t + 2, sb);
        const u16* buf = lds + cb * BUFU;
        bf16x8 af[2], bfv[4];
#pragma unroll
        for (int mi = 0; mi < 2; ++mi)
            af[mi] = *reinterpret_cast<const bf16x8*>(&buf[aoff[mi]]);
#pragma unroll
        for (int ni = 0; ni < 4; ++ni)
            bfv[ni] = *reinterpret_cast<const bf16x8*>(&buf[boff[ni]]);
        __builtin_amdgcn_s_setprio(1);
#pragma unroll
        for (int mi = 0; mi < 2; ++mi)
#pragma unroll
            for (int ni = 0; ni < 4; ++ni)
                acc[mi][ni] = __builtin_amdgcn_mfma_f32_16x16x32_bf16(
                    af[mi], bfv[ni], acc[mi][ni], 0, 0, 0);
        __builtin_amdgcn_s_setprio(0);
        if (t < 30)       asm volatile("s_waitcnt vmcnt(3)" ::: "memory");
        else if (t == 30) asm volatile("s_waitcnt vmcnt(0)" ::: "memory");
        __builtin_amdgcn_sched_barrier(0);
        __builtin_amdgcn_s_barrier();
        cb = (cb == 2) ? 0 : cb + 1;
        sb = (sb == 2) ? 0 : sb + 1;
    }
#undef STAGE

#pragma unroll
    for (int mi = 0; mi < 2; ++mi)
#pragma unroll
        for (int ni = 0; ni < 4; ++ni) {
            const int n     = n0 + wc + ni * 16 + fr;
            const int mbase = m0 + wr + mi * 16 + fq * 4;
            const float bn  = b0[n];
#pragma unroll
            for (int r = 0; r < 4; ++r)
                outF[(size_t)(mbase + r) * 1024 + n] = acc[mi][ni][r] + bn;
        }
}

// ======== per-chunk KV^T = v^T @ k, ni-split: 2048 one-wave blocks (8 waves/CU) ========
__global__ __launch_bounds__(64)
void chunk_kv_kernel(const u16* __restrict__ KbT, const u16* __restrict__ VbT,
                     u16* __restrict__ KVT)
{
    const int blk = blockIdx.x;          // (bh*NC + c)*2 + nh
    const int nh = blk & 1;
    const int bc = blk >> 1;
    const int bh = bc >> 5, c = bc & 31;
    const int lane = threadIdx.x;
    const int fr = lane & 15, fq = lane >> 4, fk = fq * 8;
    const u16* kt = KbT + (size_t)bh * 64 * 2048;
    const u16* vt = VbT + (size_t)bh * 64 * 2048;

    bf16x8 a[4][2], b[2][2];             // a = V rows (de, all), b = K rows (ni-half)
#pragma unroll
    for (int mi = 0; mi < 4; ++mi)
#pragma unroll
        for (int kh = 0; kh < 2; ++kh)
            a[mi][kh] = *reinterpret_cast<const bf16x8*>(
                &vt[(size_t)(mi * 16 + fr) * 2048 + c * 64 + kh * 32 + fk]);
#pragma unroll
    for (int ni = 0; ni < 2; ++ni)
#pragma unroll
        for (int kh = 0; kh < 2; ++kh)
            b[ni][kh] = *reinterpret_cast<const bf16x8*>(
                &kt[(size_t)((nh * 2 + ni) * 16 + fr) * 2048 + c * 64 + kh * 32 + fk]);

    f32x4 acc[4][2] = {};
    __builtin_amdgcn_s_setprio(1);
#pragma unroll
    for (int mi = 0; mi < 4; ++mi)
#pragma unroll
        for (int ni = 0; ni < 2; ++ni)
#pragma unroll
            for (int kh = 0; kh < 2; ++kh)
                acc[mi][ni] = __builtin_amdgcn_mfma_f32_16x16x32_bf16(
                    a[mi][kh], b[ni][kh], acc[mi][ni], 0, 0, 0);
    __builtin_amdgcn_s_setprio(0);

    u16* out = KVT + (size_t)bc * 4096;    // [de][dk] bf16, our dk-half
#pragma unroll
    for (int mi = 0; mi < 4; ++mi)
#pragma unroll
        for (int ni = 0; ni < 2; ++ni)
#pragma unroll
            for (int r = 0; r < 4; ++r)
                out[(mi * 16 + fq * 4 + r) * 64 + (nh * 2 + ni) * 16 + fr] =
                    f2b(acc[mi][ni][r]);
}

// ---------------- elementwise exclusive scan over chunks (bf16 in/out) ----------------
__global__ __launch_bounds__(256)
void scan_kernel(const u16* __restrict__ KVT, u16* __restrict__ STb)
{
    const int bh = blockIdx.x >> 4, sl = blockIdx.x & 15;
    const int el = sl * 256 + threadIdx.x;              // element of [de][dk]
    const u16* src = KVT + (size_t)bh * NC * 4096 + el;
    u16*      dst  = STb + (size_t)bh * NC * 4096 + el;
    float run = 0.f;
#pragma unroll 4
    for (int c = 0; c < NC; ++c) {
        dst[(size_t)c * 4096] = f2b(run);               // exclusive prefix
        run += b2f(src[(size_t)c * 4096]);
    }
}

// ======== per-chunk attention output: 2 waves/block (8 waves/CU) ========
__global__ __launch_bounds__(128)
void attn_kernel(const u16* __restrict__ Qb, const u16* __restrict__ Kb,
                 const u16* __restrict__ VbT, const u16* __restrict__ STb,
                 u16* __restrict__ Ob)
{
    __shared__ u16 P[64 * 72];   // stride 72 u16 = 144B: 16B-aligned, 2-way banks
    const int blk = blockIdx.x;
    const int bh = blk >> 5, c = blk & 31;
    const int b = bh >> 4, h = bh & 15;
    const int tid = threadIdx.x, wv = tid >> 6, lane = tid & 63;
    const int fr = lane & 15, fq = lane >> 4, fk = fq * 8;
    const int tok0 = b * 2048 + c * 64;

    bf16x8 qa[4][2];
#pragma unroll
    for (int mi = 0; mi < 4; ++mi)
#pragma unroll
        for (int kh = 0; kh < 2; ++kh)
            qa[mi][kh] = *reinterpret_cast<const bf16x8*>(
                &Qb[(size_t)(tok0 + mi * 16 + fr) * 1024 + h * 64 + kh * 32 + fk]);

    // P(:, si-half) = causal-mask(q @ k^T) -> LDS bf16
    {
        bf16x8 kb[2][2];
#pragma unroll
        for (int si = 0; si < 2; ++si)
#pragma unroll
            for (int kh = 0; kh < 2; ++kh)
                kb[si][kh] = *reinterpret_cast<const bf16x8*>(
                    &Kb[(size_t)(tok0 + (wv * 2 + si) * 16 + fr) * 1024
                        + h * 64 + kh * 32 + fk]);
        f32x4 p[4][2] = {};
        __builtin_amdgcn_s_setprio(1);
#pragma unroll
        for (int mi = 0; mi < 4; ++mi)
#pragma unroll
            for (int si = 0; si < 2; ++si)
#pragma unroll
                for (int kh = 0; kh < 2; ++kh)
                    p[mi][si] = __builtin_amdgcn_mfma_f32_16x16x32_bf16(
                        qa[mi][kh], kb[si][kh], p[mi][si], 0, 0, 0);
        __builtin_amdgcn_s_setprio(0);
#pragma unroll
        for (int mi = 0; mi < 4; ++mi)
#pragma unroll
            for (int si = 0; si < 2; ++si)
#pragma unroll
                for (int r = 0; r < 4; ++r) {
                    int t = mi * 16 + fq * 4 + r;
                    int s = (wv * 2 + si) * 16 + fr;
                    float v = (s <= t) ? p[mi][si][r] : 0.0f;
                    P[t * 72 + s] = f2b(v);
                }
    }
    __syncthreads();

    f32x4 acc[4][2] = {};
    // acc = q @ ST_half   (STb[de][dk], dk-contiguous; de = ni-half)
    {
        const u16* st = STb + (size_t)blk * 4096;
        bf16x8 sb[2][2];
#pragma unroll
        for (int ni = 0; ni < 2; ++ni)
#pragma unroll
            for (int kh = 0; kh < 2; ++kh)
                sb[ni][kh] = *reinterpret_cast<const bf16x8*>(
                    &st[((wv * 2 + ni) * 16 + fr) * 64 + kh * 32 + fk]);
        __builtin_amdgcn_s_setprio(1);
#pragma unroll
        for (int mi = 0; mi < 4; ++mi)
#pragma unroll
            for (int ni = 0; ni < 2; ++ni)
#pragma unroll
                for (int kh = 0; kh < 2; ++kh)
                    acc[mi][ni] = __builtin_amdgcn_mfma_f32_16x16x32_bf16(
                        qa[mi][kh], sb[ni][kh], acc[mi][ni], 0, 0, 0);
        __builtin_amdgcn_s_setprio(0);
    }
    // acc += P @ v_half
    {
        const u16* vt = VbT + (size_t)bh * 64 * 2048;
#pragma unroll
        for (int sh = 0; sh < 2; ++sh) {
            bf16x8 pa[4], vb[2];
#pragma unroll
            for (int mi = 0; mi < 4; ++mi)
                pa[mi] = *reinterpret_cast<const bf16x8*>(
                    &P[(mi * 16 + fr) * 72 + sh * 32 + fk]);
#pragma unroll
            for (int ni = 0; ni < 2; ++ni)
                vb[ni] = *reinterpret_cast<const bf16x8*>(
                    &vt[(size_t)((wv * 2 + ni) * 16 + fr) * 2048
                        + c * 64 + sh * 32 + fk]);
            __builtin_amdgcn_s_setprio(1);
#pragma unroll
            for (int mi = 0; mi < 4; ++mi)
#pragma unroll
                for (int ni = 0; ni < 2; ++ni)
                    acc[mi][ni] = __builtin_amdgcn_mfma_f32_16x16x32_bf16(
                        pa[mi], vb[ni], acc[mi][ni], 0, 0, 0);
            __builtin_amdgcn_s_setprio(0);
        }
    }
    // write token-major bf16 O (our ni-half columns)
#pragma unroll
    for (int mi = 0; mi < 4; ++mi)
#pragma unroll
        for (int ni = 0; ni < 2; ++ni)
#pragma unroll
            for (int r = 0; r < 4; ++r) {
                int t = tok0 + mi * 16 + fq * 4 + r;
                int n = h * 64 + (wv * 2 + ni) * 16 + fr;
                Ob[(size_t)t * 1024 + n] = f2b(acc[mi][ni][r]);
            }
}

extern "C" void kernel_launch(void* const* d_in, const int* in_sizes, int n_in,
                              void* d_out, int out_size, void* d_ws, size_t ws_size,
                              hipStream_t stream)
{
    (void)in_sizes; (void)n_in; (void)out_size; (void)ws_size;
    const float* x  = (const float*)d_in[0];
    const float* Wq = (const float*)d_in[1];
    const float* bq = (const float*)d_in[2];
    const float* Wk = (const float*)d_in[3];
    const float* bk = (const float*)d_in[4];
    const float* Wv = (const float*)d_in[5];
    const float* bv = (const float*)d_in[6];
    const float* Wo = (const float*)d_in[7];
    const float* bo = (const float*)d_in[8];
    float* out = (float*)d_out;

    char* ws = (char*)d_ws;
    constexpr size_t SZ_ME = (size_t)Mq * Eq * 2;        // 8 MB
    u16*   Qb  = (u16*)  (ws + 0 * SZ_ME);
    u16*   Kb  = (u16*)  (ws + 1 * SZ_ME);
    u16*   KbT = (u16*)  (ws + 2 * SZ_ME);
    u16*   VbT = (u16*)  (ws + 3 * SZ_ME);
    u16*   Ob  = (u16*)  (ws + 4 * SZ_ME);
    u16*   KVT = (u16*)  (ws + 5 * SZ_ME);               // 8 MB bf16
    u16*   STb = (u16*)  (ws + 6 * SZ_ME);
    u16*   Xb  = (u16*)  (ws + 7 * SZ_ME);
    u16*   Wb0 = (u16*)  (ws + 8 * SZ_ME);               // [Wq|Wk|Wv|Wo] bf16
    u16* Wqkvb = Wb0;
    u16* Wob   = Wb0 + (size_t)3 * Eq * Eq;

    // 1) all bf16 conversions, one launch
    cvt_all_kernel<<<dim3(8192), dim3(256), 0, stream>>>(x, Wq, Wk, Wv, Wo, Xb, Wb0);

    // 2) fused QKV projection (M=4096, N=3072): BK=64 ring-2, 768 blocks x 512 thr
    qkv_ring<<<dim3(768), dim3(512), 0, stream>>>(
        Xb, Wqkvb, bq, bk, bv, Qb, Kb, KbT, VbT);

    // 3) attention: ni-split chunk_kv (2048 blk), scan, 2-wave attn (1024 blk)
    chunk_kv_kernel<<<dim3(BH * NC * 2), dim3(64), 0, stream>>>(KbT, VbT, KVT);
    scan_kernel<<<dim3(BH * 16), dim3(256), 0, stream>>>(KVT, STb);
    attn_kernel<<<dim3(BH * NC), dim3(128), 0, stream>>>(Qb, Kb, VbT, STb, Ob);

    // 4) output projection (M=4096, N=1024): ring GEMM, 512 blocks (2/CU)
    oproj_kernel<<<dim3(512), dim3(256), 0, stream>>>(Ob, Wob, bo, out);
}

// Round 17
// 86.789 us; speedup vs baseline: 1.4280x; 1.0287x over previous
//
#include <hip/hip_runtime.h>
#include <hip/hip_bf16.h>
#include <cmath>

typedef unsigned short u16;
typedef __bf16 bf16x8 __attribute__((ext_vector_type(8)));
typedef float  f32x4  __attribute__((ext_vector_type(4)));
typedef float  f4     __attribute__((ext_vector_type(4)));
typedef u16    us4    __attribute__((ext_vector_type(4)));

#define DEVFN __device__ __forceinline__

static constexpr int Bq = 2, Nq = 2048, Eq = 1024;
static constexpr int Mq = Bq * Nq;        // 4096 tokens
static constexpr int CHK = 64;            // attention chunk
static constexpr int NC  = Nq / CHK;      // 32 chunks
static constexpr int BH  = Bq * 16;       // 32

DEVFN u16 f2b(float f) {                  // f32 -> bf16 (RNE), finite inputs
    union { float f; unsigned int u; } x; x.f = f;
    unsigned int r = x.u + 0x7fffu + ((x.u >> 16) & 1u);
    return (u16)(r >> 16);
}
DEVFN float b2f(u16 v) {
    union { unsigned int u; float f; } x; x.u = ((unsigned int)v) << 16; return x.f;
}

DEVFN void gl_lds16(const u16* g, u16* l) {  // async 16B global->LDS (dest: wave base + lane*16)
    __builtin_amdgcn_global_load_lds(
        (const __attribute__((address_space(1))) unsigned int*)(g),
        (__attribute__((address_space(3))) unsigned int*)(l),
        16, 0, 0);
}

// ---------------- all f32 -> bf16 converts in ONE launch ----------------
__global__ __launch_bounds__(256)
void cvt_all_kernel(const float* __restrict__ x,
                    const float* __restrict__ w0, const float* __restrict__ w1,
                    const float* __restrict__ w2, const float* __restrict__ w3,
                    u16* __restrict__ Xb, u16* __restrict__ Wb)
{
    const int blk = blockIdx.x;
    const float* s; u16* d; int i;
    if (blk < 4096) {
        i = blk * 256 + threadIdx.x;  s = x;  d = Xb;
    } else {
        const int wsel = (blk - 4096) >> 10;
        i = ((blk - 4096) & 1023) * 256 + threadIdx.x;
        s = (wsel == 0) ? w0 : (wsel == 1) ? w1 : (wsel == 2) ? w2 : w3;
        d = Wb + (size_t)wsel * (Eq * Eq);
    }
    f4 v = *reinterpret_cast<const f4*>(&s[(size_t)i * 4]);
    us4 p; p[0] = f2b(v[0]); p[1] = f2b(v[1]); p[2] = f2b(v[2]); p[3] = f2b(v[3]);
    *reinterpret_cast<us4*>(&d[(size_t)i * 4]) = p;
}

// ======== QKV ring GEMM: 128x128 tile, 8 waves (32x64), BK=64, ring-2 (R16 best) ========
__global__ __launch_bounds__(512, 4)
void qkv_ring(const u16* __restrict__ X, const u16* __restrict__ W,
              const float* __restrict__ b0, const float* __restrict__ b1,
              const float* __restrict__ b2,
              u16* __restrict__ Qb, u16* __restrict__ Kb, u16* __restrict__ KbT,
              u16* __restrict__ VbT)
{
    constexpr int BUFU = 16384;               // 32KB: A 8192 u16 | B 8192 u16
    __shared__ u16 lds[2 * BUFU];             // 64KB -> 2 blocks/CU
    const int tid = threadIdx.x, wid = tid >> 6, lane = tid & 63;
    const int wr = (wid >> 1) * 32, wc = (wid & 1) * 64;   // wave: 32 rows x 64 cols
    const int fr = lane & 15, fq = lane >> 4;

    const int bid = blockIdx.x;               // grid 768 = 8 * 96 (XCD-bijective)
    const int fid = (bid & 7) * 96 + (bid >> 3);
    const int bx = fid % 24, by = fid / 24;
    const int m0 = by * 128, n0 = bx * 128;

    // staging: one round = 512 thr x 16B = 64 rows x 8 slots; 2 rounds per matrix
    const int row0 = tid >> 3;                               // 0..63
    const int sc   = ((tid & 7) ^ (row0 & 7)) * 8;           // swizzled source slot
    const u16* gA = X + (size_t)(m0 + row0) * 1024 + sc;
    const u16* gB = W + (size_t)(n0 + row0) * 1024 + sc;
    const int dw = wid * 512;                 // wave-uniform piece within each round

    // fragment reads: same involution; rows' &7 == fr&7 (bases are mult of 16)
    int aoff[2][2], boff[2][4];
#pragma unroll
    for (int kk = 0; kk < 2; ++kk) {
        const int slot = ((kk * 4 + fq) ^ (fr & 7)) << 3;
#pragma unroll
        for (int mi = 0; mi < 2; ++mi)
            aoff[kk][mi] = (wr + mi * 16 + fr) * 64 + slot;
#pragma unroll
        for (int ni = 0; ni < 4; ++ni)
            boff[kk][ni] = 8192 + (wc + ni * 16 + fr) * 64 + slot;
    }

#define STAGE(kt, bs) do { u16* _b = lds + (bs) * BUFU;                        \
        gl_lds16(gA + (kt) * 64,              _b + dw);                        \
        gl_lds16(gA + (kt) * 64 + 64 * 1024,  _b + 4096 + dw);                 \
        gl_lds16(gB + (kt) * 64,              _b + 8192 + dw);                 \
        gl_lds16(gB + (kt) * 64 + 64 * 1024,  _b + 12288 + dw); } while (0)

    STAGE(0, 0);
    asm volatile("s_waitcnt vmcnt(0)" ::: "memory");
    __builtin_amdgcn_sched_barrier(0);
    __builtin_amdgcn_s_barrier();

    f32x4 acc[2][4] = {};

    for (int t = 0; t < 16; ++t) {
        if (t + 1 < 16) STAGE(t + 1, (t + 1) & 1);
        const u16* buf = lds + (t & 1) * BUFU;
#pragma unroll
        for (int kk = 0; kk < 2; ++kk) {
            bf16x8 af[2], bfv[4];
#pragma unroll
            for (int mi = 0; mi < 2; ++mi)
                af[mi] = *reinterpret_cast<const bf16x8*>(&buf[aoff[kk][mi]]);
#pragma unroll
            for (int ni = 0; ni < 4; ++ni)
                bfv[ni] = *reinterpret_cast<const bf16x8*>(&buf[boff[kk][ni]]);
            __builtin_amdgcn_s_setprio(1);
#pragma unroll
            for (int mi = 0; mi < 2; ++mi)
#pragma unroll
                for (int ni = 0; ni < 4; ++ni)
                    acc[mi][ni] = __builtin_amdgcn_mfma_f32_16x16x32_bf16(
                        af[mi], bfv[ni], acc[mi][ni], 0, 0, 0);
            __builtin_amdgcn_s_setprio(0);
        }
        asm volatile("s_waitcnt vmcnt(0)" ::: "memory");
        __builtin_amdgcn_sched_barrier(0);
        __builtin_amdgcn_s_barrier();
    }
#undef STAGE

    const int nw  = n0 + wc;                           // 64-aligned, seg-uniform
    const int seg = nw >> 10;                          // 0=q 1=k 2=v
    const float* bp = (seg == 0) ? b0 : (seg == 1) ? b1 : b2;
#pragma unroll
    for (int mi = 0; mi < 2; ++mi)
#pragma unroll
        for (int ni = 0; ni < 4; ++ni) {
            const int nl    = (nw & 1023) + ni * 16 + fr;
            const int mbase = m0 + wr + mi * 16 + fq * 4;
            const float bn  = bp[nl];
            float vr[4];
#pragma unroll
            for (int r = 0; r < 4; ++r) {
                float v = acc[mi][ni][r] + bn;
                if (seg < 2) v = (v > 0.f) ? (v + 1.f) : __expf(v);  // elu+1
                vr[r] = v;
            }
            if (seg == 0) {
#pragma unroll
                for (int r = 0; r < 4; ++r)
                    Qb[(size_t)(mbase + r) * 1024 + nl] = f2b(vr[r]);
            } else {
                us4 pk;
#pragma unroll
                for (int r = 0; r < 4; ++r) pk[r] = f2b(vr[r]);
                const int bb = mbase >> 11, nt = mbase & 2047;
                const int hh = nl >> 6,     dd = nl & 63;
                u16* T = (seg == 1) ? KbT : VbT;
                *reinterpret_cast<us4*>(
                    &T[((size_t)(bb * 16 + hh) * 64 + dd) * 2048 + nt]) = pk;
                if (seg == 1) {
#pragma unroll
                    for (int r = 0; r < 4; ++r)
                        Kb[(size_t)(mbase + r) * 1024 + nl] = f2b(vr[r]);
                }
            }
        }
}

// ======== O-proj: 64x128 tile, 8 waves (16x64), BK=64, ring-2 (qkv-R16 structure) ========
__global__ __launch_bounds__(512, 4)
void oproj_kernel(const u16* __restrict__ X, const u16* __restrict__ W,
                  const float* __restrict__ b0, float* __restrict__ outF)
{
    constexpr int BUFU = 12288;               // 24KB: A 4096 u16 | B 8192 u16
    __shared__ u16 lds[2 * BUFU];             // 48KB -> 3 blocks/CU
    const int tid = threadIdx.x, wid = tid >> 6, lane = tid & 63;
    const int wr = (wid >> 1) * 16, wc = (wid & 1) * 64;   // wave: 16 rows x 64 cols
    const int fr = lane & 15, fq = lane >> 4;

    const int bid = blockIdx.x;               // grid 512 = 8 * 64 (XCD-bijective)
    const int fid = (bid & 7) * 64 + (bid >> 3);
    const int bx = fid & 7, by = fid >> 3;
    const int m0 = by * 64, n0 = bx * 128;

    // staging rounds of 512 granules (64 rows x 8 slots): A 1 round, B 2 rounds
    const int row0 = tid >> 3;                               // 0..63
    const int sc   = ((tid & 7) ^ (row0 & 7)) * 8;           // swizzled source slot
    const u16* gA = X + (size_t)(m0 + row0) * 1024 + sc;
    const u16* gB = W + (size_t)(n0 + row0) * 1024 + sc;
    const int dw = wid * 512;

    int aoff[2], boff[2][4];
#pragma unroll
    for (int kk = 0; kk < 2; ++kk) {
        const int slot = ((kk * 4 + fq) ^ (fr & 7)) << 3;
        aoff[kk] = (wr + fr) * 64 + slot;
#pragma unroll
        for (int ni = 0; ni < 4; ++ni)
            boff[kk][ni] = 4096 + (wc + ni * 16 + fr) * 64 + slot;
    }

#define STAGE(kt, bs) do { u16* _b = lds + (bs) * BUFU;                        \
        gl_lds16(gA + (kt) * 64,              _b + dw);                        \
        gl_lds16(gB + (kt) * 64,              _b + 4096 + dw);                 \
        gl_lds16(gB + (kt) * 64 + 64 * 1024,  _b + 8192 + dw); } while (0)

    STAGE(0, 0);
    asm volatile("s_waitcnt vmcnt(0)" ::: "memory");
    __builtin_amdgcn_sched_barrier(0);
    __builtin_amdgcn_s_barrier();

    f32x4 acc[4] = {};

    for (int t = 0; t < 16; ++t) {
        if (t + 1 < 16) STAGE(t + 1, (t + 1) & 1);
        const u16* buf = lds + (t & 1) * BUFU;
#pragma unroll
        for (int kk = 0; kk < 2; ++kk) {
            bf16x8 af, bfv[4];
            af = *reinterpret_cast<const bf16x8*>(&buf[aoff[kk]]);
#pragma unroll
            for (int ni = 0; ni < 4; ++ni)
                bfv[ni] = *reinterpret_cast<const bf16x8*>(&buf[boff[kk][ni]]);
            __builtin_amdgcn_s_setprio(1);
#pragma unroll
            for (int ni = 0; ni < 4; ++ni)
                acc[ni] = __builtin_amdgcn_mfma_f32_16x16x32_bf16(
                    af, bfv[ni], acc[ni], 0, 0, 0);
            __builtin_amdgcn_s_setprio(0);
        }
        asm volatile("s_waitcnt vmcnt(0)" ::: "memory");
        __builtin_amdgcn_sched_barrier(0);
        __builtin_amdgcn_s_barrier();
    }
#undef STAGE

#pragma unroll
    for (int ni = 0; ni < 4; ++ni) {
        const int n     = n0 + wc + ni * 16 + fr;
        const int mbase = m0 + wr + fq * 4;
        const float bn  = b0[n];
#pragma unroll
        for (int r = 0; r < 4; ++r)
            outF[(size_t)(mbase + r) * 1024 + n] = acc[ni][r] + bn;
    }
}

// ======== per-chunk KV^T = v^T @ k, ni-split: 2048 one-wave blocks (8 waves/CU) ========
__global__ __launch_bounds__(64)
void chunk_kv_kernel(const u16* __restrict__ KbT, const u16* __restrict__ VbT,
                     u16* __restrict__ KVT)
{
    const int blk = blockIdx.x;          // (bh*NC + c)*2 + nh
    const int nh = blk & 1;
    const int bc = blk >> 1;
    const int bh = bc >> 5, c = bc & 31;
    const int lane = threadIdx.x;
    const int fr = lane & 15, fq = lane >> 4, fk = fq * 8;
    const u16* kt = KbT + (size_t)bh * 64 * 2048;
    const u16* vt = VbT + (size_t)bh * 64 * 2048;

    bf16x8 a[4][2], b[2][2];             // a = V rows (de, all), b = K rows (ni-half)
#pragma unroll
    for (int mi = 0; mi < 4; ++mi)
#pragma unroll
        for (int kh = 0; kh < 2; ++kh)
            a[mi][kh] = *reinterpret_cast<const bf16x8*>(
                &vt[(size_t)(mi * 16 + fr) * 2048 + c * 64 + kh * 32 + fk]);
#pragma unroll
    for (int ni = 0; ni < 2; ++ni)
#pragma unroll
        for (int kh = 0; kh < 2; ++kh)
            b[ni][kh] = *reinterpret_cast<const bf16x8*>(
                &kt[(size_t)((nh * 2 + ni) * 16 + fr) * 2048 + c * 64 + kh * 32 + fk]);

    f32x4 acc[4][2] = {};
    __builtin_amdgcn_s_setprio(1);
#pragma unroll
    for (int mi = 0; mi < 4; ++mi)
#pragma unroll
        for (int ni = 0; ni < 2; ++ni)
#pragma unroll
            for (int kh = 0; kh < 2; ++kh)
                acc[mi][ni] = __builtin_amdgcn_mfma_f32_16x16x32_bf16(
                    a[mi][kh], b[ni][kh], acc[mi][ni], 0, 0, 0);
    __builtin_amdgcn_s_setprio(0);

    u16* out = KVT + (size_t)bc * 4096;    // [de][dk] bf16, our dk-half
#pragma unroll
    for (int mi = 0; mi < 4; ++mi)
#pragma unroll
        for (int ni = 0; ni < 2; ++ni)
#pragma unroll
            for (int r = 0; r < 4; ++r)
                out[(mi * 16 + fq * 4 + r) * 64 + (nh * 2 + ni) * 16 + fr] =
                    f2b(acc[mi][ni][r]);
}

// ---------------- elementwise exclusive scan over chunks (bf16 in/out) ----------------
__global__ __launch_bounds__(256)
void scan_kernel(const u16* __restrict__ KVT, u16* __restrict__ STb)
{
    const int bh = blockIdx.x >> 4, sl = blockIdx.x & 15;
    const int el = sl * 256 + threadIdx.x;              // element of [de][dk]
    const u16* src = KVT + (size_t)bh * NC * 4096 + el;
    u16*      dst  = STb + (size_t)bh * NC * 4096 + el;
    float run = 0.f;
#pragma unroll 4
    for (int c = 0; c < NC; ++c) {
        dst[(size_t)c * 4096] = f2b(run);               // exclusive prefix
        run += b2f(src[(size_t)c * 4096]);
    }
}

// ======== per-chunk attention output: 2 waves/block (8 waves/CU) ========
__global__ __launch_bounds__(128)
void attn_kernel(const u16* __restrict__ Qb, const u16* __restrict__ Kb,
                 const u16* __restrict__ VbT, const u16* __restrict__ STb,
                 u16* __restrict__ Ob)
{
    __shared__ u16 P[64 * 72];   // stride 72 u16 = 144B: 16B-aligned, 2-way banks
    const int blk = blockIdx.x;
    const int bh = blk >> 5, c = blk & 31;
    const int b = bh >> 4, h = bh & 15;
    const int tid = threadIdx.x, wv = tid >> 6, lane = tid & 63;
    const int fr = lane & 15, fq = lane >> 4, fk = fq * 8;
    const int tok0 = b * 2048 + c * 64;

    bf16x8 qa[4][2];
#pragma unroll
    for (int mi = 0; mi < 4; ++mi)
#pragma unroll
        for (int kh = 0; kh < 2; ++kh)
            qa[mi][kh] = *reinterpret_cast<const bf16x8*>(
                &Qb[(size_t)(tok0 + mi * 16 + fr) * 1024 + h * 64 + kh * 32 + fk]);

    // P(:, si-half) = causal-mask(q @ k^T) -> LDS bf16
    {
        bf16x8 kb[2][2];
#pragma unroll
        for (int si = 0; si < 2; ++si)
#pragma unroll
            for (int kh = 0; kh < 2; ++kh)
                kb[si][kh] = *reinterpret_cast<const bf16x8*>(
                    &Kb[(size_t)(tok0 + (wv * 2 + si) * 16 + fr) * 1024
                        + h * 64 + kh * 32 + fk]);
        f32x4 p[4][2] = {};
        __builtin_amdgcn_s_setprio(1);
#pragma unroll
        for (int mi = 0; mi < 4; ++mi)
#pragma unroll
            for (int si = 0; si < 2; ++si)
#pragma unroll
                for (int kh = 0; kh < 2; ++kh)
                    p[mi][si] = __builtin_amdgcn_mfma_f32_16x16x32_bf16(
                        qa[mi][kh], kb[si][kh], p[mi][si], 0, 0, 0);
        __builtin_amdgcn_s_setprio(0);
#pragma unroll
        for (int mi = 0; mi < 4; ++mi)
#pragma unroll
            for (int si = 0; si < 2; ++si)
#pragma unroll
                for (int r = 0; r < 4; ++r) {
                    int t = mi * 16 + fq * 4 + r;
                    int s = (wv * 2 + si) * 16 + fr;
                    float v = (s <= t) ? p[mi][si][r] : 0.0f;
                    P[t * 72 + s] = f2b(v);
                }
    }
    __syncthreads();

    f32x4 acc[4][2] = {};
    // acc = q @ ST_half   (STb[de][dk], dk-contiguous; de = ni-half)
    {
        const u16* st = STb + (size_t)blk * 4096;
        bf16x8 sb[2][2];
#pragma unroll
        for (int ni = 0; ni < 2; ++ni)
#pragma unroll
            for (int kh = 0; kh < 2; ++kh)
                sb[ni][kh] = *reinterpret_cast<const bf16x8*>(
                    &st[((wv * 2 + ni) * 16 + fr) * 64 + kh * 32 + fk]);
        __builtin_amdgcn_s_setprio(1);
#pragma unroll
        for (int mi = 0; mi < 4; ++mi)
#pragma unroll
            for (int ni = 0; ni < 2; ++ni)
#pragma unroll
                for (int kh = 0; kh < 2; ++kh)
                    acc[mi][ni] = __builtin_amdgcn_mfma_f32_16x16x32_bf16(
                        qa[mi][kh], sb[ni][kh], acc[mi][ni], 0, 0, 0);
        __builtin_amdgcn_s_setprio(0);
    }
    // acc += P @ v_half
    {
        const u16* vt = VbT + (size_t)bh * 64 * 2048;
#pragma unroll
        for (int sh = 0; sh < 2; ++sh) {
            bf16x8 pa[4], vb[2];
#pragma unroll
            for (int mi = 0; mi < 4; ++mi)
                pa[mi] = *reinterpret_cast<const bf16x8*>(
                    &P[(mi * 16 + fr) * 72 + sh * 32 + fk]);
#pragma unroll
            for (int ni = 0; ni < 2; ++ni)
                vb[ni] = *reinterpret_cast<const bf16x8*>(
                    &vt[(size_t)((wv * 2 + ni) * 16 + fr) * 2048
                        + c * 64 + sh * 32 + fk]);
            __builtin_amdgcn_s_setprio(1);
#pragma unroll
            for (int mi = 0; mi < 4; ++mi)
#pragma unroll
                for (int ni = 0; ni < 2; ++ni)
                    acc[mi][ni] = __builtin_amdgcn_mfma_f32_16x16x32_bf16(
                        pa[mi], vb[ni], acc[mi][ni], 0, 0, 0);
            __builtin_amdgcn_s_setprio(0);
        }
    }
    // write token-major bf16 O (our ni-half columns)
#pragma unroll
    for (int mi = 0; mi < 4; ++mi)
#pragma unroll
        for (int ni = 0; ni < 2; ++ni)
#pragma unroll
            for (int r = 0; r < 4; ++r) {
                int t = tok0 + mi * 16 + fq * 4 + r;
                int n = h * 64 + (wv * 2 + ni) * 16 + fr;
                Ob[(size_t)t * 1024 + n] = f2b(acc[mi][ni][r]);
            }
}

extern "C" void kernel_launch(void* const* d_in, const int* in_sizes, int n_in,
                              void* d_out, int out_size, void* d_ws, size_t ws_size,
                              hipStream_t stream)
{
    (void)in_sizes; (void)n_in; (void)out_size; (void)ws_size;
    const float* x  = (const float*)d_in[0];
    const float* Wq = (const float*)d_in[1];
    const float* bq = (const float*)d_in[2];
    const float* Wk = (const float*)d_in[3];
    const float* bk = (const float*)d_in[4];
    const float* Wv = (const float*)d_in[5];
    const float* bv = (const float*)d_in[6];
    const float* Wo = (const float*)d_in[7];
    const float* bo = (const float*)d_in[8];
    float* out = (float*)d_out;

    char* ws = (char*)d_ws;
    constexpr size_t SZ_ME = (size_t)Mq * Eq * 2;        // 8 MB
    u16*   Qb  = (u16*)  (ws + 0 * SZ_ME);
    u16*   Kb  = (u16*)  (ws + 1 * SZ_ME);
    u16*   KbT = (u16*)  (ws + 2 * SZ_ME);
    u16*   VbT = (u16*)  (ws + 3 * SZ_ME);
    u16*   Ob  = (u16*)  (ws + 4 * SZ_ME);
    u16*   KVT = (u16*)  (ws + 5 * SZ_ME);               // 8 MB bf16
    u16*   STb = (u16*)  (ws + 6 * SZ_ME);
    u16*   Xb  = (u16*)  (ws + 7 * SZ_ME);
    u16*   Wb0 = (u16*)  (ws + 8 * SZ_ME);               // [Wq|Wk|Wv|Wo] bf16
    u16* Wqkvb = Wb0;
    u16* Wob   = Wb0 + (size_t)3 * Eq * Eq;

    // 1) all bf16 conversions, one launch
    cvt_all_kernel<<<dim3(8192), dim3(256), 0, stream>>>(x, Wq, Wk, Wv, Wo, Xb, Wb0);

    // 2) fused QKV projection (M=4096, N=3072): BK=64 ring-2, 768 blocks x 512 thr
    qkv_ring<<<dim3(768), dim3(512), 0, stream>>>(
        Xb, Wqkvb, bq, bk, bv, Qb, Kb, KbT, VbT);

    // 3) attention: ni-split chunk_kv (2048 blk), scan, 2-wave attn (1024 blk)
    chunk_kv_kernel<<<dim3(BH * NC * 2), dim3(64), 0, stream>>>(KbT, VbT, KVT);
    scan_kernel<<<dim3(BH * 16), dim3(256), 0, stream>>>(KVT, STb);
    attn_kernel<<<dim3(BH * NC), dim3(128), 0, stream>>>(Qb, Kb, VbT, STb, Ob);

    // 4) output projection (M=4096, N=1024): BK=64 ring-2, 512 blocks x 512 thr
    oproj_kernel<<<dim3(512), dim3(512), 0, stream>>>(Ob, Wob, bo, out);
}